// Round 1
// baseline (2457.849 us; speedup 1.0000x reference)
//
#include <hip/hip_runtime.h>

typedef unsigned short u16;
typedef __attribute__((ext_vector_type(4))) float f32x4;
typedef __attribute__((ext_vector_type(8))) short s16x8;
typedef __attribute__((ext_vector_type(8))) u16 u16x8;
typedef __attribute__((ext_vector_type(4))) u16 u16x4;

#define NB 16
#define CD 512
#define NS 4096
#define NHD 8

__device__ __forceinline__ float bf2f(u16 u){
  union { unsigned int i; float f; } z; z.i = ((unsigned int)u) << 16; return z.f;
}
__device__ __forceinline__ u16 f2bf(float f){
  union { float f; unsigned int i; } z; z.f = f;
  unsigned int i = z.i;
  return (u16)((i + 0x7fffu + ((i >> 16) & 1u)) >> 16);
}
__device__ __forceinline__ float gelu_f(float x){
  return 0.5f * x * (1.0f + erff(x * 0.70710678118654752440f));
}

__device__ __forceinline__ void store_c(u16* p, float v){ *p = f2bf(v); }
__device__ __forceinline__ void store_c(float* p, float v){ *p = v; }

// ---------------- K0: weights -> bf16 (g1 folded into w_qkv) ----------------
__global__ void prep_w_k(const float* __restrict__ wqkv, const float* __restrict__ g1,
                         const float* __restrict__ wout, u16* __restrict__ w1b,
                         u16* __restrict__ w2b){
  int i = blockIdx.x * 256 + threadIdx.x;
  if (i < 1536*512) {
    w1b[i] = f2bf(wqkv[i] * g1[i & 511]);
  } else {
    int j = i - 1536*512;
    w2b[j] = f2bf(wout[j]);
  }
}

// ------- K1: ChanLN over c, write x_ln transposed [b][n][c] as bf16 --------
__global__ __launch_bounds__(256) void ln1t_k(const float* __restrict__ fmap,
                                              u16* __restrict__ xlnT){
  int b = blockIdx.y, n0 = blockIdx.x * 64;
  int t = threadIdx.x, nl = t & 63, qd = t >> 6;
  __shared__ float ps[4][64], ps2[4][64], mean_s[64], rstd_s[64];
  __shared__ u16 tile[64][72];

  const float* fb = fmap + (size_t)b*CD*NS + n0 + nl;
  float s = 0.f, s2 = 0.f;
  for (int c = qd*128; c < qd*128 + 128; ++c){
    float v = fb[(size_t)c*NS]; s += v; s2 += v*v;
  }
  ps[qd][nl] = s; ps2[qd][nl] = s2;
  __syncthreads();
  if (t < 64){
    float ss  = ps[0][t]+ps[1][t]+ps[2][t]+ps[3][t];
    float ss2 = ps2[0][t]+ps2[1][t]+ps2[2][t]+ps2[3][t];
    float mn  = ss * (1.f/512.f);
    float var = ss2 * (1.f/512.f) - mn*mn;
    mean_s[t] = mn; rstd_s[t] = rsqrtf(var + 1e-5f);
  }
  __syncthreads();

  for (int ct = 0; ct < 8; ++ct){
    #pragma unroll
    for (int it = 0; it < 4; ++it){
      int q = t + it*256;
      int cl = q >> 4, ch = q & 15;
      int c = ct*64 + cl;
      f32x4 x = *(const f32x4*)&fmap[(size_t)b*CD*NS + (size_t)c*NS + n0 + ch*4];
      u16x4 pk;
      #pragma unroll
      for (int j = 0; j < 4; ++j){
        int nn = ch*4 + j;
        pk[j] = f2bf((x[j] - mean_s[nn]) * rstd_s[nn]);
      }
      *(u16x4*)&tile[cl][ch*4] = pk;
    }
    __syncthreads();
    #pragma unroll
    for (int it = 0; it < 2; ++it){
      int q = t + it*256;
      int nr = q >> 3, cc = q & 7;
      u16x8 pk;
      #pragma unroll
      for (int j = 0; j < 8; ++j) pk[j] = tile[cc*8 + j][nr];
      *(u16x8*)&xlnT[((size_t)b*NS + n0 + nr)*CD + ct*64 + cc*8] = pk;
    }
    __syncthreads();
  }
}

// ------------- K2/K6: bf16 MFMA GEMM  C[b][o][n] = A[o][c] * B[b][n][c]^T ---
// A: [M][512] bf16 (K contiguous), B: [b][4096][512] bf16 (K contiguous)
template<typename OUT_T>
__global__ __launch_bounds__(256) void gemm_k(const u16* __restrict__ A,
                                              const u16* __restrict__ Bm,
                                              OUT_T* __restrict__ Cm, int M){
  __shared__ u16 Al[128][72];
  __shared__ u16 Bl[128][72];
  int bb = blockIdx.z;
  int n0 = blockIdx.x*128, o0 = blockIdx.y*128;
  int t = threadIdx.x;
  int lane = t & 63, wv = t >> 6, wr = wv >> 1, wc = wv & 1;
  int fr = lane & 15, fg = lane >> 4;
  const u16* Ab = A + (size_t)o0*512;
  const u16* Bb = Bm + ((size_t)bb*NS + n0)*512;

  f32x4 acc[4][4];
  #pragma unroll
  for (int i=0;i<4;++i)
    #pragma unroll
    for (int j=0;j<4;++j) acc[i][j] = (f32x4){0.f,0.f,0.f,0.f};

  for (int kt = 0; kt < 512; kt += 64){
    #pragma unroll
    for (int it = 0; it < 4; ++it){
      int q = t + it*256;
      int row = q >> 3, cc = q & 7;
      *(u16x8*)&Al[row][cc*8] = *(const u16x8*)&Ab[(size_t)row*512 + kt + cc*8];
      *(u16x8*)&Bl[row][cc*8] = *(const u16x8*)&Bb[(size_t)row*512 + kt + cc*8];
    }
    __syncthreads();
    #pragma unroll
    for (int kk = 0; kk < 64; kk += 32){
      s16x8 af[4], bfr[4];
      #pragma unroll
      for (int i=0;i<4;++i){
        af[i]  = *(const s16x8*)&Al[wr*64 + i*16 + fr][kk + fg*8];
        bfr[i] = *(const s16x8*)&Bl[wc*64 + i*16 + fr][kk + fg*8];
      }
      #pragma unroll
      for (int i=0;i<4;++i)
        #pragma unroll
        for (int j=0;j<4;++j)
          acc[i][j] = __builtin_amdgcn_mfma_f32_16x16x32_bf16(af[i], bfr[j], acc[i][j], 0,0,0);
    }
    __syncthreads();
  }
  size_t cb = (size_t)bb * M * NS;
  #pragma unroll
  for (int i=0;i<4;++i)
    #pragma unroll
    for (int j=0;j<4;++j){
      int row = o0 + wr*64 + i*16 + fg*4;
      int col = n0 + wc*64 + j*16 + fr;
      #pragma unroll
      for (int r=0;r<4;++r)
        store_c(&Cm[cb + (size_t)(row+r)*NS + col], acc[i][j][r]);
    }
}

// ---------------- K3: k-softmax stats (max & sumexp over n) per (b, row) ----
__global__ __launch_bounds__(256) void kstats_k(const u16* __restrict__ qkv,
                                                float* __restrict__ kM, float* __restrict__ kS){
  int orr = blockIdx.x, b = blockIdx.y, t = threadIdx.x;
  const u16* kr = qkv + ((size_t)(b*1536 + 512 + orr))*NS;
  float v[16];
  #pragma unroll
  for (int i=0;i<16;++i) v[i] = bf2f(kr[t + i*256]);
  float m = v[0];
  #pragma unroll
  for (int i=1;i<16;++i) m = fmaxf(m, v[i]);
  #pragma unroll
  for (int off=32; off; off>>=1) m = fmaxf(m, __shfl_xor(m, off, 64));
  __shared__ float wm[4], wsum[4];
  if ((t&63)==0) wm[t>>6] = m;
  __syncthreads();
  m = fmaxf(fmaxf(wm[0],wm[1]), fmaxf(wm[2],wm[3]));
  float s = 0.f;
  #pragma unroll
  for (int i=0;i<16;++i) s += __expf(v[i]-m);
  #pragma unroll
  for (int off=32; off; off>>=1) s += __shfl_xor(s, off, 64);
  if ((t&63)==0) wsum[t>>6] = s;
  __syncthreads();
  if (t==0){ kM[b*512+orr] = m; kS[b*512+orr] = wsum[0]+wsum[1]+wsum[2]+wsum[3]; }
}

// ------- K4: context partials: ctx[d][e] += softmax_k/4096 * v_l2norm ------
__global__ __launch_bounds__(256) void ctxpart_k(const u16* __restrict__ qkv,
                                                 const float* __restrict__ kM,
                                                 const float* __restrict__ kS,
                                                 float* __restrict__ part){
  int chunk = blockIdx.x, bh = blockIdx.y;
  int b = bh >> 3, h = bh & 7;
  int t = threadIdx.x;
  __shared__ float ekl[64][65];
  __shared__ float vl[64][65];
  __shared__ float mh[64], sh[64], invn[64];
  if (t < 64){
    mh[t] = kM[b*512 + h*64 + t];
    sh[t] = 1.0f / (kS[b*512 + h*64 + t] * 4096.0f);
  }
  float acc[4][4];
  #pragma unroll
  for (int i=0;i<4;++i)
    #pragma unroll
    for (int j=0;j<4;++j) acc[i][j] = 0.f;
  int tl_ = t & 15, te = t >> 4;
  const u16* kb = qkv + ((size_t)(b*1536 + 512  + h*64))*NS;
  const u16* vb = qkv + ((size_t)(b*1536 + 1024 + h*64))*NS;

  for (int sc = 0; sc < 8; ++sc){
    int n0 = chunk*512 + sc*64;
    __syncthreads();
    #pragma unroll
    for (int it=0; it<16; ++it){
      int idx = t + it*256;
      int row = idx >> 6, col = idx & 63;
      float kv = bf2f(kb[(size_t)row*NS + n0 + col]);
      ekl[row][col] = __expf(kv - mh[row]) * sh[row];
      vl[row][col]  = bf2f(vb[(size_t)row*NS + n0 + col]);
    }
    __syncthreads();
    if (t < 64){
      float ss = 0.f;
      for (int e=0;e<64;++e){ float x = vl[e][t]; ss += x*x; }
      invn[t] = rsqrtf(ss);
    }
    __syncthreads();
    #pragma unroll
    for (int it=0; it<16; ++it){
      int idx = t + it*256;
      int row = idx >> 6, col = idx & 63;
      vl[row][col] *= invn[col];
    }
    __syncthreads();
    for (int nn=0; nn<64; ++nn){
      float av[4], bv[4];
      #pragma unroll
      for (int i=0;i<4;++i){ av[i] = ekl[tl_*4+i][nn]; bv[i] = vl[te*4+i][nn]; }
      #pragma unroll
      for (int i=0;i<4;++i)
        #pragma unroll
        for (int j=0;j<4;++j) acc[i][j] += av[i]*bv[j];
    }
  }
  float* pp = part + ((size_t)bh*8 + chunk)*4096;
  #pragma unroll
  for (int i=0;i<4;++i)
    #pragma unroll
    for (int j=0;j<4;++j) pp[(tl_*4+i)*64 + te*4+j] = acc[i][j];
}

// ---------------- K4b: reduce 8 partials -> ctx[bh][64*64] -----------------
__global__ void ctxred_k(const float* __restrict__ part, float* __restrict__ ctx){
  int bh = blockIdx.x, t = threadIdx.x;
  #pragma unroll
  for (int i=0;i<16;++i){
    int idx = t + i*256;
    float s = 0.f;
    #pragma unroll
    for (int ch=0; ch<8; ++ch) s += part[((size_t)bh*8 + ch)*4096 + idx];
    ctx[(size_t)bh*4096 + idx] = s;
  }
}

// ------- K5: out = softmax_feat(q)*scale @ ctx, GELU, write gT[b][n][c] ----
__global__ __launch_bounds__(256) void attnout_k(const u16* __restrict__ qkv,
                                                 const float* __restrict__ ctx,
                                                 u16* __restrict__ gT){
  int bh = blockIdx.y;
  int b = bh >> 3, h = bh & 7;
  int n0 = blockIdx.x * 256;
  int t = threadIdx.x;
  __shared__ float cl[4096];
  const float* cs = ctx + (size_t)bh*4096;
  #pragma unroll
  for (int i=0;i<16;++i) cl[t + i*256] = cs[t + i*256];
  __syncthreads();
  int n = n0 + t;
  const u16* qb = qkv + ((size_t)(b*1536 + h*64))*NS + n;
  float p[64];
  #pragma unroll
  for (int d=0; d<64; ++d) p[d] = bf2f(qb[(size_t)d*NS]);
  float m = p[0];
  #pragma unroll
  for (int d=1; d<64; ++d) m = fmaxf(m, p[d]);
  float s = 0.f;
  #pragma unroll
  for (int d=0; d<64; ++d){ p[d] = __expf(p[d]-m); s += p[d]; }
  float inv = 0.125f / s;
  size_t gbase = ((size_t)b*NS + n)*CD + h*64;
  for (int eo=0; eo<8; ++eo){
    f32x4 a0 = {0.f,0.f,0.f,0.f}, a1 = {0.f,0.f,0.f,0.f};
    #pragma unroll
    for (int d=0; d<64; ++d){
      const f32x4* cp = (const f32x4*)&cl[d*64 + eo*8];
      a0 += p[d] * cp[0];
      a1 += p[d] * cp[1];
    }
    u16x8 pk;
    #pragma unroll
    for (int j=0;j<4;++j){
      pk[j]   = f2bf(gelu_f(a0[j]*inv));
      pk[4+j] = f2bf(gelu_f(a1[j]*inv));
    }
    *(u16x8*)&gT[gbase + eo*8] = pk;
  }
}

// ---------------- K7: final ChanLN over c, write fp32 d_out ----------------
__global__ __launch_bounds__(256) void ln2_k(const float* __restrict__ y,
                                             const float* __restrict__ g2,
                                             float* __restrict__ out){
  int b = blockIdx.y, n0 = blockIdx.x * 64;
  int t = threadIdx.x, nl = t & 63, qd = t >> 6;
  __shared__ float ps[4][64], ps2[4][64], mean_s[64], rstd_s[64];
  const float* yb = y + (size_t)b*CD*NS + n0 + nl;
  float s = 0.f, s2 = 0.f;
  for (int c = qd*128; c < qd*128 + 128; ++c){
    float v = yb[(size_t)c*NS]; s += v; s2 += v*v;
  }
  ps[qd][nl] = s; ps2[qd][nl] = s2;
  __syncthreads();
  if (t < 64){
    float ss  = ps[0][t]+ps[1][t]+ps[2][t]+ps[3][t];
    float ss2 = ps2[0][t]+ps2[1][t]+ps2[2][t]+ps2[3][t];
    float mn  = ss * (1.f/512.f);
    float var = ss2 * (1.f/512.f) - mn*mn;
    mean_s[t] = mn; rstd_s[t] = rsqrtf(var + 1e-5f);
  }
  __syncthreads();
  float* ob = out + (size_t)b*CD*NS + n0 + nl;
  for (int c = qd*128; c < qd*128 + 128; ++c){
    float v = yb[(size_t)c*NS];
    ob[(size_t)c*NS] = (v - mean_s[nl]) * rstd_s[nl] * g2[c];
  }
}

extern "C" void kernel_launch(void* const* d_in, const int* in_sizes, int n_in,
                              void* d_out, int out_size, void* d_ws, size_t ws_size,
                              hipStream_t stream) {
  const float* fmap = (const float*)d_in[0];
  const float* g1   = (const float*)d_in[1];
  const float* wqkv = (const float*)d_in[2];
  const float* wout = (const float*)d_in[3];
  const float* g2   = (const float*)d_in[4];
  float* out = (float*)d_out;

  char* ws = (char*)d_ws;
  size_t off = 0;
  auto alloc = [&](size_t bytes) -> void* {
    void* p = ws + off;
    off += (bytes + 255) & ~(size_t)255;
    return p;
  };
  // qkv bf16 [16][1536][4096]; later reused as y fp32 [16][512][4096]
  u16*   qkv  = (u16*)alloc((size_t)16*1536*4096*2);
  float* y    = (float*)qkv;
  // xlnT bf16 [16][4096][512]; later reused as gT bf16 [16][4096][512]
  u16*   xlnT = (u16*)alloc((size_t)16*4096*512*2);
  u16*   gT   = xlnT;
  float* kM   = (float*)alloc((size_t)16*512*4);
  float* kS   = (float*)alloc((size_t)16*512*4);
  float* part = (float*)alloc((size_t)128*8*4096*4);
  float* ctx  = (float*)alloc((size_t)128*4096*4);
  u16*   w1b  = (u16*)alloc((size_t)1536*512*2);
  u16*   w2b  = (u16*)alloc((size_t)512*512*2);
  if (off > ws_size) return;  // workspace too small -> loud failure

  prep_w_k<<<4096, 256, 0, stream>>>(wqkv, g1, wout, w1b, w2b);
  ln1t_k<<<dim3(64,16), 256, 0, stream>>>(fmap, xlnT);
  gemm_k<u16><<<dim3(32,12,16), 256, 0, stream>>>(w1b, xlnT, qkv, 1536);
  kstats_k<<<dim3(512,16), 256, 0, stream>>>(qkv, kM, kS);
  ctxpart_k<<<dim3(8,128), 256, 0, stream>>>(qkv, kM, kS, part);
  ctxred_k<<<128, 256, 0, stream>>>(part, ctx);
  attnout_k<<<dim3(16,128), 256, 0, stream>>>(qkv, ctx, gT);
  gemm_k<float><<<dim3(32,4,16), 256, 0, stream>>>(w2b, gT, y, 512);
  ln2_k<<<dim3(64,16), 256, 0, stream>>>(y, g2, out);
}

// Round 2
// 546.189 us; speedup vs baseline: 4.5000x; 4.5000x over previous
//
#include <hip/hip_runtime.h>

typedef unsigned short u16;
typedef __attribute__((ext_vector_type(4))) float f32x4;
typedef __attribute__((ext_vector_type(8))) short s16x8;
typedef __attribute__((ext_vector_type(8))) u16 u16x8;
typedef __attribute__((ext_vector_type(4))) u16 u16x4;

#define NB 16
#define CD 512
#define NS 4096
#define NHD 8

__device__ __forceinline__ float bf2f(u16 u){
  union { unsigned int i; float f; } z; z.i = ((unsigned int)u) << 16; return z.f;
}
__device__ __forceinline__ u16 f2bf(float f){
  union { float f; unsigned int i; } z; z.f = f;
  unsigned int i = z.i;
  return (u16)((i + 0x7fffu + ((i >> 16) & 1u)) >> 16);
}
__device__ __forceinline__ float gelu_f(float x){
  return 0.5f * x * (1.0f + erff(x * 0.70710678118654752440f));
}
__device__ __forceinline__ void gl_lds16(const u16* g, u16* l){
  __builtin_amdgcn_global_load_lds((const __attribute__((address_space(1))) void*)(g),
                                   (__attribute__((address_space(3))) void*)(l), 16, 0, 0);
}

__device__ __forceinline__ void store_c(u16* p, float v){ *p = f2bf(v); }
__device__ __forceinline__ void store_c(float* p, float v){ *p = v; }

// ---------------- K0: weights -> bf16 (g1 folded into w_qkv) ----------------
__global__ void prep_w_k(const float* __restrict__ wqkv, const float* __restrict__ g1,
                         const float* __restrict__ wout, u16* __restrict__ w1b,
                         u16* __restrict__ w2b){
  int i = blockIdx.x * 256 + threadIdx.x;
  if (i < 1536*512) {
    w1b[i] = f2bf(wqkv[i] * g1[i & 511]);
  } else {
    int j = i - 1536*512;
    w2b[j] = f2bf(wout[j]);
  }
}

// ------- K1: ChanLN over c, write x_ln transposed [b][n][c] as bf16 --------
__global__ __launch_bounds__(256) void ln1t_k(const float* __restrict__ fmap,
                                              u16* __restrict__ xlnT){
  int b = blockIdx.y, n0 = blockIdx.x * 64;
  int t = threadIdx.x, nl = t & 63, qd = t >> 6;
  __shared__ float ps[4][64], ps2[4][64], mean_s[64], rstd_s[64];
  __shared__ u16 tile[64][72];

  const float* fb = fmap + (size_t)b*CD*NS + n0 + nl;
  float s = 0.f, s2 = 0.f;
  for (int c = qd*128; c < qd*128 + 128; ++c){
    float v = fb[(size_t)c*NS]; s += v; s2 += v*v;
  }
  ps[qd][nl] = s; ps2[qd][nl] = s2;
  __syncthreads();
  if (t < 64){
    float ss  = ps[0][t]+ps[1][t]+ps[2][t]+ps[3][t];
    float ss2 = ps2[0][t]+ps2[1][t]+ps2[2][t]+ps2[3][t];
    float mn  = ss * (1.f/512.f);
    float var = ss2 * (1.f/512.f) - mn*mn;
    mean_s[t] = mn; rstd_s[t] = rsqrtf(var + 1e-5f);
  }
  __syncthreads();

  for (int ct = 0; ct < 8; ++ct){
    #pragma unroll
    for (int it = 0; it < 4; ++it){
      int q = t + it*256;
      int cl = q >> 4, ch = q & 15;
      int c = ct*64 + cl;
      f32x4 x = *(const f32x4*)&fmap[(size_t)b*CD*NS + (size_t)c*NS + n0 + ch*4];
      u16x4 pk;
      #pragma unroll
      for (int j = 0; j < 4; ++j){
        int nn = ch*4 + j;
        pk[j] = f2bf((x[j] - mean_s[nn]) * rstd_s[nn]);
      }
      *(u16x4*)&tile[cl][ch*4] = pk;
    }
    __syncthreads();
    #pragma unroll
    for (int it = 0; it < 2; ++it){
      int q = t + it*256;
      int nr = q >> 3, cc = q & 7;
      u16x8 pk;
      #pragma unroll
      for (int j = 0; j < 8; ++j) pk[j] = tile[cc*8 + j][nr];
      *(u16x8*)&xlnT[((size_t)b*NS + n0 + nr)*CD + ct*64 + cc*8] = pk;
    }
    __syncthreads();
  }
}

// ------------- K2/K6: bf16 MFMA GEMM  C[b][o][n] = A[o][c] * B[b][n][c]^T ---
// A: [M][512] bf16 (K contiguous), B: [b][4096][512] bf16 (K contiguous)
// m97 pattern: linear LDS + global_load_lds width 16, 2-barrier K loop.
template<typename OUT_T>
__global__ __launch_bounds__(256) void gemm_k(const u16* __restrict__ A,
                                              const u16* __restrict__ Bm,
                                              OUT_T* __restrict__ Cm, int M){
  __shared__ u16 Al[128*64];
  __shared__ u16 Bl[128*64];
  int bb = blockIdx.z;
  int n0 = blockIdx.x*128, o0 = blockIdx.y*128;
  int t = threadIdx.x;
  int lane = t & 63, wv = t >> 6, wr = wv >> 1, wc = wv & 1;
  int fr = lane & 15, fg = lane >> 4;
  const u16* Ab = A + (size_t)o0*512;
  const u16* Bb = Bm + ((size_t)bb*NS + n0)*512;

  f32x4 acc[4][4];
  #pragma unroll
  for (int i=0;i<4;++i)
    #pragma unroll
    for (int j=0;j<4;++j) acc[i][j] = (f32x4){0.f,0.f,0.f,0.f};

  for (int kt = 0; kt < 512; kt += 64){
    // stage 16KB each of A,B: issue slot (wv*4+it), lane writes base+lane*16
    #pragma unroll
    for (int it = 0; it < 4; ++it){
      int off  = (wv*4 + it)*1024 + lane*16;   // byte offset in 128x64 u16 buffer
      int row  = off >> 7;                     // 128B per row
      int cole = (off & 127) >> 1;             // element col within 64
      gl_lds16(Ab + (size_t)row*512 + kt + cole, &Al[(wv*4 + it)*512]);
      gl_lds16(Bb + (size_t)row*512 + kt + cole, &Bl[(wv*4 + it)*512]);
    }
    __syncthreads();
    #pragma unroll
    for (int kk = 0; kk < 64; kk += 32){
      s16x8 af[4], bfr[4];
      #pragma unroll
      for (int i=0;i<4;++i){
        af[i]  = *(const s16x8*)&Al[(wr*64 + i*16 + fr)*64 + kk + fg*8];
        bfr[i] = *(const s16x8*)&Bl[(wc*64 + i*16 + fr)*64 + kk + fg*8];
      }
      #pragma unroll
      for (int i=0;i<4;++i)
        #pragma unroll
        for (int j=0;j<4;++j)
          acc[i][j] = __builtin_amdgcn_mfma_f32_16x16x32_bf16(af[i], bfr[j], acc[i][j], 0,0,0);
    }
    __syncthreads();
  }
  size_t cb = (size_t)bb * M * NS;
  #pragma unroll
  for (int i=0;i<4;++i)
    #pragma unroll
    for (int j=0;j<4;++j){
      int row = o0 + wr*64 + i*16 + fg*4;
      int col = n0 + wc*64 + j*16 + fr;
      #pragma unroll
      for (int r=0;r<4;++r)
        store_c(&Cm[cb + (size_t)(row+r)*NS + col], acc[i][j][r]);
    }
}

// ---------------- K3: k-softmax stats (max & sumexp over n) per (b, row) ----
__global__ __launch_bounds__(256) void kstats_k(const u16* __restrict__ qkv,
                                                float* __restrict__ kM, float* __restrict__ kS){
  int orr = blockIdx.x, b = blockIdx.y, t = threadIdx.x;
  const u16* kr = qkv + ((size_t)(b*1536 + 512 + orr))*NS;
  float v[16];
  #pragma unroll
  for (int i=0;i<16;++i) v[i] = bf2f(kr[t + i*256]);
  float m = v[0];
  #pragma unroll
  for (int i=1;i<16;++i) m = fmaxf(m, v[i]);
  #pragma unroll
  for (int off=32; off; off>>=1) m = fmaxf(m, __shfl_xor(m, off, 64));
  __shared__ float wm[4], wsum[4];
  if ((t&63)==0) wm[t>>6] = m;
  __syncthreads();
  m = fmaxf(fmaxf(wm[0],wm[1]), fmaxf(wm[2],wm[3]));
  float s = 0.f;
  #pragma unroll
  for (int i=0;i<16;++i) s += __expf(v[i]-m);
  #pragma unroll
  for (int off=32; off; off>>=1) s += __shfl_xor(s, off, 64);
  if ((t&63)==0) wsum[t>>6] = s;
  __syncthreads();
  if (t==0){ kM[b*512+orr] = m; kS[b*512+orr] = wsum[0]+wsum[1]+wsum[2]+wsum[3]; }
}

// ------- K4: context partials: ctx[d][e] += softmax_k/4096 * v_l2norm ------
__global__ __launch_bounds__(256) void ctxpart_k(const u16* __restrict__ qkv,
                                                 const float* __restrict__ kM,
                                                 const float* __restrict__ kS,
                                                 float* __restrict__ part){
  int chunk = blockIdx.x, bh = blockIdx.y;
  int b = bh >> 3, h = bh & 7;
  int t = threadIdx.x;
  __shared__ float ekl[64][65];
  __shared__ float vl[64][65];
  __shared__ float mh[64], sh[64], invn[64];
  if (t < 64){
    mh[t] = kM[b*512 + h*64 + t];
    sh[t] = 1.0f / (kS[b*512 + h*64 + t] * 4096.0f);
  }
  float acc[4][4];
  #pragma unroll
  for (int i=0;i<4;++i)
    #pragma unroll
    for (int j=0;j<4;++j) acc[i][j] = 0.f;
  int tl_ = t & 15, te = t >> 4;
  const u16* kb = qkv + ((size_t)(b*1536 + 512  + h*64))*NS;
  const u16* vb = qkv + ((size_t)(b*1536 + 1024 + h*64))*NS;

  for (int sc = 0; sc < 8; ++sc){
    int n0 = chunk*512 + sc*64;
    __syncthreads();
    #pragma unroll
    for (int it=0; it<16; ++it){
      int idx = t + it*256;
      int row = idx >> 6, col = idx & 63;
      float kv = bf2f(kb[(size_t)row*NS + n0 + col]);
      ekl[row][col] = __expf(kv - mh[row]) * sh[row];
      vl[row][col]  = bf2f(vb[(size_t)row*NS + n0 + col]);
    }
    __syncthreads();
    if (t < 64){
      float ss = 0.f;
      for (int e=0;e<64;++e){ float x = vl[e][t]; ss += x*x; }
      invn[t] = rsqrtf(ss);
    }
    __syncthreads();
    #pragma unroll
    for (int it=0; it<16; ++it){
      int idx = t + it*256;
      int row = idx >> 6, col = idx & 63;
      vl[row][col] *= invn[col];
    }
    __syncthreads();
    for (int nn=0; nn<64; ++nn){
      float av[4], bv[4];
      #pragma unroll
      for (int i=0;i<4;++i){ av[i] = ekl[tl_*4+i][nn]; bv[i] = vl[te*4+i][nn]; }
      #pragma unroll
      for (int i=0;i<4;++i)
        #pragma unroll
        for (int j=0;j<4;++j) acc[i][j] += av[i]*bv[j];
    }
  }
  float* pp = part + ((size_t)bh*8 + chunk)*4096;
  #pragma unroll
  for (int i=0;i<4;++i)
    #pragma unroll
    for (int j=0;j<4;++j) pp[(tl_*4+i)*64 + te*4+j] = acc[i][j];
}

// ---------------- K4b: reduce 8 partials -> ctx[bh][64*64] -----------------
__global__ void ctxred_k(const float* __restrict__ part, float* __restrict__ ctx){
  int bh = blockIdx.x, t = threadIdx.x;
  #pragma unroll
  for (int i=0;i<16;++i){
    int idx = t + i*256;
    float s = 0.f;
    #pragma unroll
    for (int ch=0; ch<8; ++ch) s += part[((size_t)bh*8 + ch)*4096 + idx];
    ctx[(size_t)bh*4096 + idx] = s;
  }
}

// ------- K5: out = softmax_feat(q)*scale @ ctx  via MFMA, GELU, gT[b][n][c] -
// P (bf16, softmax'd q rows) in LDS [256][72]; ctx^T bf16 [64][72];
// 4 waves x (4x4 frags, K=64) mfma; epilogue gelu -> LDS -> coalesced write.
__global__ __launch_bounds__(256) void attnout_k(const u16* __restrict__ qkv,
                                                 const float* __restrict__ ctx,
                                                 u16* __restrict__ gT){
  int bh = blockIdx.y;
  int b = bh >> 3, h = bh & 7;
  int n0 = blockIdx.x * 256;
  int t = threadIdx.x;
  int lane = t & 63, wv = t >> 6;
  int fr = lane & 15, fg = lane >> 4;
  __shared__ u16 P[256][72];
  __shared__ u16 cT[64][72];

  // ctx transpose -> bf16 cT[e][d]
  const float* cs = ctx + (size_t)bh*4096;
  #pragma unroll
  for (int i=0;i<16;++i){
    int idx = i*256 + t;
    int d = idx >> 6, e = idx & 63;
    cT[e][d] = f2bf(cs[idx]);
  }

  // per-thread softmax over d for n = n0 + t
  const u16* qb = qkv + ((size_t)(b*1536 + h*64))*NS + n0 + t;
  float p[64];
  #pragma unroll
  for (int d=0; d<64; ++d) p[d] = bf2f(qb[(size_t)d*NS]);
  float m = p[0];
  #pragma unroll
  for (int d=1; d<64; ++d) m = fmaxf(m, p[d]);
  float s = 0.f;
  #pragma unroll
  for (int d=0; d<64; ++d){ p[d] = __expf(p[d]-m); s += p[d]; }
  float inv = 0.125f / s;   // scale = dh^-0.5 folded in
  #pragma unroll
  for (int d0=0; d0<8; ++d0){
    u16x8 pk;
    #pragma unroll
    for (int j=0;j<8;++j) pk[j] = f2bf(p[d0*8+j] * inv);
    *(u16x8*)&P[t][d0*8] = pk;
  }
  __syncthreads();

  // MFMA: out[n][e], wave wv owns n rows wv*64..wv*64+63
  f32x4 acc[4][4];
  #pragma unroll
  for (int i=0;i<4;++i)
    #pragma unroll
    for (int j=0;j<4;++j) acc[i][j] = (f32x4){0.f,0.f,0.f,0.f};
  #pragma unroll
  for (int k=0; k<2; ++k){
    s16x8 af[4], bfr[4];
    #pragma unroll
    for (int i=0;i<4;++i){
      af[i]  = *(const s16x8*)&P[wv*64 + i*16 + fr][k*32 + fg*8];
      bfr[i] = *(const s16x8*)&cT[i*16 + fr][k*32 + fg*8];
    }
    #pragma unroll
    for (int i=0;i<4;++i)
      #pragma unroll
      for (int j=0;j<4;++j)
        acc[i][j] = __builtin_amdgcn_mfma_f32_16x16x32_bf16(af[i], bfr[j], acc[i][j], 0,0,0);
  }

  // gelu + stage into own P rows (only this wave ever touches them)
  #pragma unroll
  for (int i=0;i<4;++i)
    #pragma unroll
    for (int j=0;j<4;++j)
      #pragma unroll
      for (int r=0;r<4;++r)
        P[wv*64 + i*16 + fg*4 + r][j*16 + fr] = f2bf(gelu_f(acc[i][j][r]));

  // coalesced write: per iter 4 rows x 16 lanes x 8B = fully covered lines
  int sub = lane >> 4, e4 = (lane & 15) * 4;
  #pragma unroll
  for (int it=0; it<16; ++it){
    int row = wv*64 + it*4 + sub;
    *(u16x4*)&gT[((size_t)b*NS + n0 + row)*CD + h*64 + e4] = *(u16x4*)&P[row][e4];
  }
}

// ---------------- K7: final ChanLN over c, write fp32 d_out ----------------
__global__ __launch_bounds__(256) void ln2_k(const float* __restrict__ y,
                                             const float* __restrict__ g2,
                                             float* __restrict__ out){
  int b = blockIdx.y, n0 = blockIdx.x * 64;
  int t = threadIdx.x, nl = t & 63, qd = t >> 6;
  __shared__ float ps[4][64], ps2[4][64], mean_s[64], rstd_s[64];
  const float* yb = y + (size_t)b*CD*NS + n0 + nl;
  float s = 0.f, s2 = 0.f;
  for (int c = qd*128; c < qd*128 + 128; ++c){
    float v = yb[(size_t)c*NS]; s += v; s2 += v*v;
  }
  ps[qd][nl] = s; ps2[qd][nl] = s2;
  __syncthreads();
  if (t < 64){
    float ss  = ps[0][t]+ps[1][t]+ps[2][t]+ps[3][t];
    float ss2 = ps2[0][t]+ps2[1][t]+ps2[2][t]+ps2[3][t];
    float mn  = ss * (1.f/512.f);
    float var = ss2 * (1.f/512.f) - mn*mn;
    mean_s[t] = mn; rstd_s[t] = rsqrtf(var + 1e-5f);
  }
  __syncthreads();
  float* ob = out + (size_t)b*CD*NS + n0 + nl;
  for (int c = qd*128; c < qd*128 + 128; ++c){
    float v = yb[(size_t)c*NS];
    ob[(size_t)c*NS] = (v - mean_s[nl]) * rstd_s[nl] * g2[c];
  }
}

extern "C" void kernel_launch(void* const* d_in, const int* in_sizes, int n_in,
                              void* d_out, int out_size, void* d_ws, size_t ws_size,
                              hipStream_t stream) {
  const float* fmap = (const float*)d_in[0];
  const float* g1   = (const float*)d_in[1];
  const float* wqkv = (const float*)d_in[2];
  const float* wout = (const float*)d_in[3];
  const float* g2   = (const float*)d_in[4];
  float* out = (float*)d_out;

  char* ws = (char*)d_ws;
  size_t off = 0;
  auto alloc = [&](size_t bytes) -> void* {
    void* p = ws + off;
    off += (bytes + 255) & ~(size_t)255;
    return p;
  };
  // qkv bf16 [16][1536][4096]; later reused as y fp32 [16][512][4096]
  u16*   qkv  = (u16*)alloc((size_t)16*1536*4096*2);
  float* y    = (float*)qkv;
  // xlnT bf16 [16][4096][512]; later reused as gT bf16 [16][4096][512]
  u16*   xlnT = (u16*)alloc((size_t)16*4096*512*2);
  u16*   gT   = xlnT;
  float* kM   = (float*)alloc((size_t)16*512*4);
  float* kS   = (float*)alloc((size_t)16*512*4);
  float* part = (float*)alloc((size_t)128*8*4096*4);
  float* ctx  = (float*)alloc((size_t)128*4096*4);
  u16*   w1b  = (u16*)alloc((size_t)1536*512*2);
  u16*   w2b  = (u16*)alloc((size_t)512*512*2);
  if (off > ws_size) return;  // workspace too small -> loud failure

  prep_w_k<<<4096, 256, 0, stream>>>(wqkv, g1, wout, w1b, w2b);
  ln1t_k<<<dim3(64,16), 256, 0, stream>>>(fmap, xlnT);
  gemm_k<u16><<<dim3(32,12,16), 256, 0, stream>>>(w1b, xlnT, qkv, 1536);
  kstats_k<<<dim3(512,16), 256, 0, stream>>>(qkv, kM, kS);
  ctxpart_k<<<dim3(8,128), 256, 0, stream>>>(qkv, kM, kS, part);
  ctxred_k<<<128, 256, 0, stream>>>(part, ctx);
  attnout_k<<<dim3(16,128), 256, 0, stream>>>(qkv, ctx, gT);
  gemm_k<float><<<dim3(32,4,16), 256, 0, stream>>>(w2b, gT, y, 512);
  ln2_k<<<dim3(64,16), 256, 0, stream>>>(y, g2, out);
}

// Round 3
// 488.283 us; speedup vs baseline: 5.0337x; 1.1186x over previous
//
#include <hip/hip_runtime.h>

typedef unsigned short u16;
typedef __attribute__((ext_vector_type(2))) float f32x2;
typedef __attribute__((ext_vector_type(4))) float f32x4;
typedef __attribute__((ext_vector_type(8))) short s16x8;
typedef __attribute__((ext_vector_type(8))) u16 u16x8;
typedef __attribute__((ext_vector_type(4))) u16 u16x4;

#define NB 16
#define CD 512
#define NS 4096
#define NHD 8

__device__ __forceinline__ float bf2f(u16 u){
  union { unsigned int i; float f; } z; z.i = ((unsigned int)u) << 16; return z.f;
}
__device__ __forceinline__ u16 f2bf(float f){
  union { float f; unsigned int i; } z; z.f = f;
  unsigned int i = z.i;
  return (u16)((i + 0x7fffu + ((i >> 16) & 1u)) >> 16);
}
__device__ __forceinline__ float gelu_f(float x){
  return 0.5f * x * (1.0f + erff(x * 0.70710678118654752440f));
}
__device__ __forceinline__ void gl_lds16(const u16* g, u16* l){
  __builtin_amdgcn_global_load_lds((const __attribute__((address_space(1))) void*)(g),
                                   (__attribute__((address_space(3))) void*)(l), 16, 0, 0);
}

__device__ __forceinline__ void store_c(u16* p, float v){ *p = f2bf(v); }
__device__ __forceinline__ void store_c(float* p, float v){ *p = v; }

// ---------------- K0: weights -> bf16 (g1 folded into w_qkv) ----------------
__global__ void prep_w_k(const float* __restrict__ wqkv, const float* __restrict__ g1,
                         const float* __restrict__ wout, u16* __restrict__ w1b,
                         u16* __restrict__ w2b){
  int i = blockIdx.x * 256 + threadIdx.x;
  if (i < 1536*512) {
    w1b[i] = f2bf(wqkv[i] * g1[i & 511]);
  } else {
    int j = i - 1536*512;
    w2b[j] = f2bf(wout[j]);
  }
}

// ------- K1: ChanLN over c, write x_ln transposed [b][n][c] as bf16 --------
__global__ __launch_bounds__(256) void ln1t_k(const float* __restrict__ fmap,
                                              u16* __restrict__ xlnT){
  int b = blockIdx.y, n0 = blockIdx.x * 64;
  int t = threadIdx.x, nl = t & 63, qd = t >> 6;
  __shared__ float ps[4][64], ps2[4][64], mean_s[64], rstd_s[64];
  __shared__ u16 tile[64][72];

  const float* fb = fmap + (size_t)b*CD*NS + n0 + nl;
  float s = 0.f, s2 = 0.f;
  for (int c = qd*128; c < qd*128 + 128; ++c){
    float v = fb[(size_t)c*NS]; s += v; s2 += v*v;
  }
  ps[qd][nl] = s; ps2[qd][nl] = s2;
  __syncthreads();
  if (t < 64){
    float ss  = ps[0][t]+ps[1][t]+ps[2][t]+ps[3][t];
    float ss2 = ps2[0][t]+ps2[1][t]+ps2[2][t]+ps2[3][t];
    float mn  = ss * (1.f/512.f);
    float var = ss2 * (1.f/512.f) - mn*mn;
    mean_s[t] = mn; rstd_s[t] = rsqrtf(var + 1e-5f);
  }
  __syncthreads();

  for (int ct = 0; ct < 8; ++ct){
    #pragma unroll
    for (int it = 0; it < 4; ++it){
      int q = t + it*256;
      int cl = q >> 4, ch = q & 15;
      int c = ct*64 + cl;
      f32x4 x = *(const f32x4*)&fmap[(size_t)b*CD*NS + (size_t)c*NS + n0 + ch*4];
      u16x4 pk;
      #pragma unroll
      for (int j = 0; j < 4; ++j){
        int nn = ch*4 + j;
        pk[j] = f2bf((x[j] - mean_s[nn]) * rstd_s[nn]);
      }
      *(u16x4*)&tile[cl][ch*4] = pk;
    }
    __syncthreads();
    #pragma unroll
    for (int it = 0; it < 2; ++it){
      int q = t + it*256;
      int nr = q >> 3, cc = q & 7;
      u16x8 pk;
      #pragma unroll
      for (int j = 0; j < 8; ++j) pk[j] = tile[cc*8 + j][nr];
      *(u16x8*)&xlnT[((size_t)b*NS + n0 + nr)*CD + ct*64 + cc*8] = pk;
    }
    __syncthreads();
  }
}

// ------------- K2/K6: bf16 MFMA GEMM  C[b][o][n] = A[o][c] * B[b][n][c]^T ---
// Double-buffered 2-phase: STAGE(t+1) issued before compute(t); one
// vmcnt(0)+barrier per K-step (the __syncthreads drain). STATS: per-block
// channel partial sums (s1,s2) per n for the fused final LN.
template<typename OUT_T, bool STATS>
__global__ __launch_bounds__(256) void gemm_k(const u16* __restrict__ A,
                                              const u16* __restrict__ Bm,
                                              OUT_T* __restrict__ Cm, int M,
                                              float* __restrict__ stats){
  __shared__ u16 Al[2][128*64];
  __shared__ u16 Bl[2][128*64];
  int bb = blockIdx.z;
  int n0 = blockIdx.x*128, o0 = blockIdx.y*128;
  int t = threadIdx.x;
  int lane = t & 63, wv = t >> 6, wr = wv >> 1, wc = wv & 1;
  int fr = lane & 15, fg = lane >> 4;
  const u16* Ab = A + (size_t)o0*512;
  const u16* Bb = Bm + ((size_t)bb*NS + n0)*512;

  f32x4 acc[4][4];
  #pragma unroll
  for (int i=0;i<4;++i)
    #pragma unroll
    for (int j=0;j<4;++j) acc[i][j] = (f32x4){0.f,0.f,0.f,0.f};

  auto stage = [&](int buf, int kt){
    #pragma unroll
    for (int it = 0; it < 4; ++it){
      int slot = wv*4 + it;
      int off  = slot*1024 + lane*16;   // byte offset in 128x64 u16 buffer
      int row  = off >> 7;              // 128B per row
      int cole = (off & 127) >> 1;      // element col within 64
      gl_lds16(Ab + (size_t)row*512 + kt + cole, &Al[buf][slot*512]);
      gl_lds16(Bb + (size_t)row*512 + kt + cole, &Bl[buf][slot*512]);
    }
  };

  stage(0, 0);
  __syncthreads();
  for (int ki = 0; ki < 8; ++ki){
    int cur = ki & 1;
    if (ki < 7) stage(cur^1, (ki+1)*64);   // loads fly under MFMA
    #pragma unroll
    for (int kk = 0; kk < 64; kk += 32){
      s16x8 af[4], bfr[4];
      #pragma unroll
      for (int i=0;i<4;++i){
        af[i]  = *(const s16x8*)&Al[cur][(wr*64 + i*16 + fr)*64 + kk + fg*8];
        bfr[i] = *(const s16x8*)&Bl[cur][(wc*64 + i*16 + fr)*64 + kk + fg*8];
      }
      #pragma unroll
      for (int i=0;i<4;++i)
        #pragma unroll
        for (int j=0;j<4;++j)
          acc[i][j] = __builtin_amdgcn_mfma_f32_16x16x32_bf16(af[i], bfr[j], acc[i][j], 0,0,0);
    }
    __syncthreads();   // vmcnt(0)+lgkmcnt(0)+barrier: next buf ready, cur consumed
  }
  size_t cb = (size_t)bb * M * NS;
  #pragma unroll
  for (int i=0;i<4;++i)
    #pragma unroll
    for (int j=0;j<4;++j){
      int row = o0 + wr*64 + i*16 + fg*4;
      int col = n0 + wc*64 + j*16 + fr;
      #pragma unroll
      for (int r=0;r<4;++r)
        store_c(&Cm[cb + (size_t)(row+r)*NS + col], acc[i][j][r]);
    }

  if constexpr (STATS){
    // per-thread: sum over its 16 rows (i,r) for each of 4 cols (j)
    float s1[4], s2[4];
    #pragma unroll
    for (int j=0;j<4;++j){
      float a = 0.f, b2 = 0.f;
      #pragma unroll
      for (int i=0;i<4;++i)
        #pragma unroll
        for (int r=0;r<4;++r){ float v = acc[i][j][r]; a += v; b2 += v*v; }
      s1[j] = a; s2[j] = b2;
    }
    // reduce over fg (lanes 16 apart) -> wave's 64 rows
    #pragma unroll
    for (int off=16; off<64; off<<=1)
      #pragma unroll
      for (int j=0;j<4;++j){
        s1[j] += __shfl_xor(s1[j], off, 64);
        s2[j] += __shfl_xor(s2[j], off, 64);
      }
    float* red = (float*)Al;   // staging dead after final barrier
    if (fg == 0){
      #pragma unroll
      for (int j=0;j<4;++j){
        red[wv*64 + j*16 + fr]       = s1[j];
        red[256 + wv*64 + j*16 + fr] = s2[j];
      }
    }
    __syncthreads();
    if (t < 128){
      int wcc = t >> 6, jf = t & 63;
      float a1 = red[wcc*64 + jf] + red[(wcc+2)*64 + jf];
      float a2 = red[256 + wcc*64 + jf] + red[256 + (wcc+2)*64 + jf];
      int n = n0 + wcc*64 + jf;
      size_t sb = ((size_t)(bb*4 + blockIdx.y)*2)*NS;
      stats[sb + n]      = a1;
      stats[sb + NS + n] = a2;
    }
  }
}

// ---------------- K3: k-softmax stats (max & sumexp over n) per (b, row) ----
__global__ __launch_bounds__(256) void kstats_k(const u16* __restrict__ qkv,
                                                float* __restrict__ kM, float* __restrict__ kS){
  int orr = blockIdx.x, b = blockIdx.y, t = threadIdx.x;
  const u16* kr = qkv + ((size_t)(b*1536 + 512 + orr))*NS + t*16;
  u16x8 va = *(const u16x8*)kr;
  u16x8 vb = *(const u16x8*)(kr + 8);
  float v[16];
  #pragma unroll
  for (int i=0;i<8;++i){ v[i] = bf2f(va[i]); v[8+i] = bf2f(vb[i]); }
  float m = v[0];
  #pragma unroll
  for (int i=1;i<16;++i) m = fmaxf(m, v[i]);
  #pragma unroll
  for (int off=32; off; off>>=1) m = fmaxf(m, __shfl_xor(m, off, 64));
  __shared__ float wm[4], wsum[4];
  if ((t&63)==0) wm[t>>6] = m;
  __syncthreads();
  m = fmaxf(fmaxf(wm[0],wm[1]), fmaxf(wm[2],wm[3]));
  float s = 0.f;
  #pragma unroll
  for (int i=0;i<16;++i) s += __expf(v[i]-m);
  #pragma unroll
  for (int off=32; off; off>>=1) s += __shfl_xor(s, off, 64);
  if ((t&63)==0) wsum[t>>6] = s;
  __syncthreads();
  if (t==0){ kM[b*512+orr] = m; kS[b*512+orr] = wsum[0]+wsum[1]+wsum[2]+wsum[3]; }
}

// ------- K4: context partials via MFMA: ctx[d][e] = sum_n ek'[d][n]*v[e][n] -
// ek' = exp(k-m)/(S*4096) * invn[n]  (invn folded into ek so v stays raw).
// LDS tiles [64][128] bf16 XOR-swizzled (col ^ ((row&7)<<3)) for b128 reads.
__global__ __launch_bounds__(256) void ctxpart_k(const u16* __restrict__ qkv,
                                                 const float* __restrict__ kM,
                                                 const float* __restrict__ kS,
                                                 float* __restrict__ part){
  int chunk = blockIdx.x, bh = blockIdx.y;
  int b = bh >> 3, h = bh & 7;
  int t = threadIdx.x;
  int lane = t & 63, wv = t >> 6;
  int fr = lane & 15, fg = lane >> 4;
  __shared__ u16 KT[64*128];
  __shared__ u16 VT[64*128];
  __shared__ float invn_s[128];
  __shared__ float mh[64], sh[64];
  if (t < 64){
    mh[t] = kM[b*512 + h*64 + t];
    sh[t] = 1.0f / (kS[b*512 + h*64 + t] * 4096.0f);
  }
  const u16* kb = qkv + ((size_t)(b*1536 + 512  + h*64))*NS;
  const u16* vb = qkv + ((size_t)(b*1536 + 1024 + h*64))*NS;
  int d = t >> 2, q = t & 3;

  f32x4 acc[4][4];
  #pragma unroll
  for (int i=0;i<4;++i)
    #pragma unroll
    for (int j=0;j<4;++j) acc[i][j] = (f32x4){0.f,0.f,0.f,0.f};

  for (int nt = 0; nt < 4; ++nt){
    int n0 = chunk*512 + nt*128;
    if (nt) __syncthreads();           // prev MFMA reads done before overwrite
    u16x8 kreg[4];
    #pragma unroll
    for (int s = 0; s < 4; ++s){
      int c0 = q*32 + s*8;
      u16x8 vv = *(const u16x8*)&vb[(size_t)d*NS + n0 + c0];
      *(u16x8*)&VT[d*128 + (c0 ^ ((d&7)<<3))] = vv;
      kreg[s] = *(const u16x8*)&kb[(size_t)d*NS + n0 + c0];
    }
    __syncthreads();
    if (t < 128){
      float ss = 0.f;
      #pragma unroll
      for (int e = 0; e < 64; ++e){
        float x = bf2f(VT[e*128 + (t ^ ((e&7)<<3))]);
        ss += x*x;
      }
      invn_s[t] = rsqrtf(ss);
    }
    __syncthreads();
    float mm = mh[d], sc = sh[d];
    #pragma unroll
    for (int s = 0; s < 4; ++s){
      int c0 = q*32 + s*8;
      u16x8 kk = kreg[s];
      u16x8 ek;
      #pragma unroll
      for (int j = 0; j < 8; ++j)
        ek[j] = f2bf(__expf(bf2f(kk[j]) - mm) * sc * invn_s[c0 + j]);
      *(u16x8*)&KT[d*128 + (c0 ^ ((d&7)<<3))] = ek;
    }
    __syncthreads();
    // wave wv takes k-slice [wv*32, wv*32+32)
    int kc = wv*32 + fg*8;
    s16x8 af[4], bfr[4];
    #pragma unroll
    for (int i=0;i<4;++i){
      int ra = i*16 + fr;
      af[i]  = *(const s16x8*)&KT[ra*128 + (kc ^ ((ra&7)<<3))];
      bfr[i] = *(const s16x8*)&VT[ra*128 + (kc ^ ((ra&7)<<3))];
    }
    #pragma unroll
    for (int i=0;i<4;++i)
      #pragma unroll
      for (int j=0;j<4;++j)
        acc[i][j] = __builtin_amdgcn_mfma_f32_16x16x32_bf16(af[i], bfr[j], acc[i][j], 0,0,0);
  }

  // cross-wave reduce (waves hold disjoint-K partials of the same 64x64 C)
  float* buf0 = (float*)KT;   // 4096 floats
  float* buf1 = (float*)VT;
  auto dump = [&](float* bf){
    #pragma unroll
    for (int i=0;i<4;++i)
      #pragma unroll
      for (int j=0;j<4;++j)
        #pragma unroll
        for (int r=0;r<4;++r) bf[((i*4+j)*4+r)*64 + lane] = acc[i][j][r];
  };
  auto addin = [&](float* bf){
    #pragma unroll
    for (int i=0;i<4;++i)
      #pragma unroll
      for (int j=0;j<4;++j)
        #pragma unroll
        for (int r=0;r<4;++r) acc[i][j][r] += bf[((i*4+j)*4+r)*64 + lane];
  };
  __syncthreads();
  if (wv==1) dump(buf0);
  if (wv==3) dump(buf1);
  __syncthreads();
  if (wv==0) addin(buf0);
  if (wv==2) addin(buf1);
  __syncthreads();
  if (wv==2) dump(buf0);
  __syncthreads();
  if (wv==0){
    addin(buf0);
    float* pp = part + ((size_t)bh*8 + chunk)*4096;
    #pragma unroll
    for (int i=0;i<4;++i)
      #pragma unroll
      for (int j=0;j<4;++j)
        #pragma unroll
        for (int r=0;r<4;++r)
          pp[(i*16+fg*4+r)*64 + j*16+fr] = acc[i][j][r];
  }
}

// ---------------- K4b: reduce 8 partials -> ctx[bh][64*64] -----------------
__global__ void ctxred_k(const float* __restrict__ part, float* __restrict__ ctx){
  int bh = blockIdx.x, t = threadIdx.x;
  #pragma unroll
  for (int i=0;i<16;++i){
    int idx = t + i*256;
    float s = 0.f;
    #pragma unroll
    for (int ch=0; ch<8; ++ch) s += part[((size_t)bh*8 + ch)*4096 + idx];
    ctx[(size_t)bh*4096 + idx] = s;
  }
}

// ------- K5: out = softmax_feat(q)*scale @ ctx  via MFMA, GELU, gT[b][n][c] -
__global__ __launch_bounds__(256) void attnout_k(const u16* __restrict__ qkv,
                                                 const float* __restrict__ ctx,
                                                 u16* __restrict__ gT){
  int bh = blockIdx.y;
  int b = bh >> 3, h = bh & 7;
  int n0 = blockIdx.x * 256;
  int t = threadIdx.x;
  int lane = t & 63, wv = t >> 6;
  int fr = lane & 15, fg = lane >> 4;
  __shared__ u16 P[256][72];
  __shared__ u16 cT[64][72];

  const float* cs = ctx + (size_t)bh*4096;
  #pragma unroll
  for (int i=0;i<16;++i){
    int idx = i*256 + t;
    int d = idx >> 6, e = idx & 63;
    cT[e][d] = f2bf(cs[idx]);
  }

  const u16* qb = qkv + ((size_t)(b*1536 + h*64))*NS + n0 + t;
  float p[64];
  #pragma unroll
  for (int d=0; d<64; ++d) p[d] = bf2f(qb[(size_t)d*NS]);
  float m = p[0];
  #pragma unroll
  for (int d=1; d<64; ++d) m = fmaxf(m, p[d]);
  float s = 0.f;
  #pragma unroll
  for (int d=0; d<64; ++d){ p[d] = __expf(p[d]-m); s += p[d]; }
  float inv = 0.125f / s;
  #pragma unroll
  for (int d0=0; d0<8; ++d0){
    u16x8 pk;
    #pragma unroll
    for (int j=0;j<8;++j) pk[j] = f2bf(p[d0*8+j] * inv);
    *(u16x8*)&P[t][d0*8] = pk;
  }
  __syncthreads();

  f32x4 acc[4][4];
  #pragma unroll
  for (int i=0;i<4;++i)
    #pragma unroll
    for (int j=0;j<4;++j) acc[i][j] = (f32x4){0.f,0.f,0.f,0.f};
  #pragma unroll
  for (int k=0; k<2; ++k){
    s16x8 af[4], bfr[4];
    #pragma unroll
    for (int i=0;i<4;++i){
      af[i]  = *(const s16x8*)&P[wv*64 + i*16 + fr][k*32 + fg*8];
      bfr[i] = *(const s16x8*)&cT[i*16 + fr][k*32 + fg*8];
    }
    #pragma unroll
    for (int i=0;i<4;++i)
      #pragma unroll
      for (int j=0;j<4;++j)
        acc[i][j] = __builtin_amdgcn_mfma_f32_16x16x32_bf16(af[i], bfr[j], acc[i][j], 0,0,0);
  }

  #pragma unroll
  for (int i=0;i<4;++i)
    #pragma unroll
    for (int j=0;j<4;++j)
      #pragma unroll
      for (int r=0;r<4;++r)
        P[wv*64 + i*16 + fg*4 + r][j*16 + fr] = f2bf(gelu_f(acc[i][j][r]));

  int sub = lane >> 4, e4 = (lane & 15) * 4;
  #pragma unroll
  for (int it=0; it<16; ++it){
    int row = wv*64 + it*4 + sub;
    *(u16x4*)&gT[((size_t)b*NS + n0 + row)*CD + h*64 + e4] = *(u16x4*)&P[row][e4];
  }
}

// -------- K7: final ChanLN (stats precomputed in gemm2), single pass -------
__global__ __launch_bounds__(256) void ln2_k(const float* __restrict__ y,
                                             const float* __restrict__ stats,
                                             const float* __restrict__ g2,
                                             float* __restrict__ out){
  int b = blockIdx.y, n0 = blockIdx.x * 128;
  int t = threadIdx.x;
  int nl = (t & 63) * 2, cg = t >> 6;   // thread owns 2 n's; wave-uniform c range
  float s1a=0.f, s1b=0.f, s2a=0.f, s2b=0.f;
  #pragma unroll
  for (int ob=0; ob<4; ++ob){
    size_t sb = ((size_t)(b*4 + ob)*2)*NS + n0 + nl;
    s1a += stats[sb];      s1b += stats[sb+1];
    s2a += stats[sb+NS];   s2b += stats[sb+NS+1];
  }
  float mna = s1a*(1.f/512.f), mnb = s1b*(1.f/512.f);
  float ra = rsqrtf(s2a*(1.f/512.f) - mna*mna + 1e-5f);
  float rb = rsqrtf(s2b*(1.f/512.f) - mnb*mnb + 1e-5f);
  const float* yb = y + (size_t)b*CD*NS + n0 + nl;
  float* ob_ = out + (size_t)b*CD*NS + n0 + nl;
  for (int c = cg*128; c < cg*128 + 128; ++c){
    f32x2 v = *(const f32x2*)&yb[(size_t)c*NS];
    float g = g2[c];
    f32x2 o;
    o[0] = (v[0]-mna)*ra*g;
    o[1] = (v[1]-mnb)*rb*g;
    *(f32x2*)&ob_[(size_t)c*NS] = o;
  }
}

extern "C" void kernel_launch(void* const* d_in, const int* in_sizes, int n_in,
                              void* d_out, int out_size, void* d_ws, size_t ws_size,
                              hipStream_t stream) {
  const float* fmap = (const float*)d_in[0];
  const float* g1   = (const float*)d_in[1];
  const float* wqkv = (const float*)d_in[2];
  const float* wout = (const float*)d_in[3];
  const float* g2   = (const float*)d_in[4];
  float* out = (float*)d_out;

  char* ws = (char*)d_ws;
  size_t off = 0;
  auto alloc = [&](size_t bytes) -> void* {
    void* p = ws + off;
    off += (bytes + 255) & ~(size_t)255;
    return p;
  };
  u16*   qkv  = (u16*)alloc((size_t)16*1536*4096*2);   // reused as y fp32
  float* y    = (float*)qkv;
  u16*   xlnT = (u16*)alloc((size_t)16*4096*512*2);    // reused as gT
  u16*   gT   = xlnT;
  float* kM    = (float*)alloc((size_t)16*512*4);
  float* kS    = (float*)alloc((size_t)16*512*4);
  float* part  = (float*)alloc((size_t)128*8*4096*4);
  float* ctx   = (float*)alloc((size_t)128*4096*4);
  float* stats = (float*)alloc((size_t)16*4*2*4096*4);
  u16*   w1b  = (u16*)alloc((size_t)1536*512*2);
  u16*   w2b  = (u16*)alloc((size_t)512*512*2);
  if (off > ws_size) return;

  prep_w_k<<<4096, 256, 0, stream>>>(wqkv, g1, wout, w1b, w2b);
  ln1t_k<<<dim3(64,16), 256, 0, stream>>>(fmap, xlnT);
  gemm_k<u16,false><<<dim3(32,12,16), 256, 0, stream>>>(w1b, xlnT, qkv, 1536, nullptr);
  kstats_k<<<dim3(512,16), 256, 0, stream>>>(qkv, kM, kS);
  ctxpart_k<<<dim3(8,128), 256, 0, stream>>>(qkv, kM, kS, part);
  ctxred_k<<<128, 256, 0, stream>>>(part, ctx);
  attnout_k<<<dim3(16,128), 256, 0, stream>>>(qkv, ctx, gT);
  gemm_k<float,true><<<dim3(32,4,16), 256, 0, stream>>>(w2b, gT, y, 512, stats);
  ln2_k<<<dim3(32,16), 256, 0, stream>>>(y, stats, g2, out);
}

// Round 4
// 435.881 us; speedup vs baseline: 5.6388x; 1.1202x over previous
//
#include <hip/hip_runtime.h>

typedef unsigned short u16;
typedef __attribute__((ext_vector_type(2))) float f32x2;
typedef __attribute__((ext_vector_type(4))) float f32x4;
typedef __attribute__((ext_vector_type(8))) short s16x8;
typedef __attribute__((ext_vector_type(8))) u16 u16x8;
typedef __attribute__((ext_vector_type(4))) u16 u16x4;

#define NB 16
#define CD 512
#define NS 4096
#define NHD 8

#define SBAR  __builtin_amdgcn_s_barrier()
#define SCHED __builtin_amdgcn_sched_barrier(0)
#define LGKM0 asm volatile("s_waitcnt lgkmcnt(0)" ::: "memory")
#define VM0   asm volatile("s_waitcnt vmcnt(0)" ::: "memory")

__device__ __forceinline__ float bf2f(u16 u){
  union { unsigned int i; float f; } z; z.i = ((unsigned int)u) << 16; return z.f;
}
__device__ __forceinline__ u16 f2bf(float f){
  union { float f; unsigned int i; } z; z.f = f;
  unsigned int i = z.i;
  return (u16)((i + 0x7fffu + ((i >> 16) & 1u)) >> 16);
}
__device__ __forceinline__ float gelu_f(float x){
  return 0.5f * x * (1.0f + erff(x * 0.70710678118654752440f));
}
__device__ __forceinline__ void gl_lds16(const u16* g, u16* l){
  __builtin_amdgcn_global_load_lds((const __attribute__((address_space(1))) void*)(g),
                                   (__attribute__((address_space(3))) void*)(l), 16, 0, 0);
}

__device__ __forceinline__ void store_c(u16* p, float v){ *p = f2bf(v); }
__device__ __forceinline__ void store_c(float* p, float v){ *p = v; }

// ---------------- K0: weights -> bf16 (g1 folded into w_qkv) ----------------
__global__ void prep_w_k(const float* __restrict__ wqkv, const float* __restrict__ g1,
                         const float* __restrict__ wout, u16* __restrict__ w1b,
                         u16* __restrict__ w2b){
  int i = blockIdx.x * 256 + threadIdx.x;
  if (i < 1536*512) {
    w1b[i] = f2bf(wqkv[i] * g1[i & 511]);
  } else {
    int j = i - 1536*512;
    w2b[j] = f2bf(wout[j]);
  }
}

// ------- K1: ChanLN over c, write x_ln transposed [b][n][c] as bf16 --------
__global__ __launch_bounds__(256) void ln1t_k(const float* __restrict__ fmap,
                                              u16* __restrict__ xlnT){
  int b = blockIdx.y, n0 = blockIdx.x * 64;
  int t = threadIdx.x, nl = t & 63, qd = t >> 6;
  __shared__ float ps[4][64], ps2[4][64], mean_s[64], rstd_s[64];
  __shared__ u16 tile[64][72];

  const float* fb = fmap + (size_t)b*CD*NS + n0 + nl;
  float s = 0.f, s2 = 0.f;
  for (int c = qd*128; c < qd*128 + 128; ++c){
    float v = fb[(size_t)c*NS]; s += v; s2 += v*v;
  }
  ps[qd][nl] = s; ps2[qd][nl] = s2;
  __syncthreads();
  if (t < 64){
    float ss  = ps[0][t]+ps[1][t]+ps[2][t]+ps[3][t];
    float ss2 = ps2[0][t]+ps2[1][t]+ps2[2][t]+ps2[3][t];
    float mn  = ss * (1.f/512.f);
    float var = ss2 * (1.f/512.f) - mn*mn;
    mean_s[t] = mn; rstd_s[t] = rsqrtf(var + 1e-5f);
  }
  __syncthreads();

  for (int ct = 0; ct < 8; ++ct){
    #pragma unroll
    for (int it = 0; it < 4; ++it){
      int q = t + it*256;
      int cl = q >> 4, ch = q & 15;
      int c = ct*64 + cl;
      f32x4 x = *(const f32x4*)&fmap[(size_t)b*CD*NS + (size_t)c*NS + n0 + ch*4];
      u16x4 pk;
      #pragma unroll
      for (int j = 0; j < 4; ++j){
        int nn = ch*4 + j;
        pk[j] = f2bf((x[j] - mean_s[nn]) * rstd_s[nn]);
      }
      *(u16x4*)&tile[cl][ch*4] = pk;
    }
    __syncthreads();
    #pragma unroll
    for (int it = 0; it < 2; ++it){
      int q = t + it*256;
      int nr = q >> 3, cc = q & 7;
      u16x8 pk;
      #pragma unroll
      for (int j = 0; j < 8; ++j) pk[j] = tile[cc*8 + j][nr];
      *(u16x8*)&xlnT[((size_t)b*NS + n0 + nr)*CD + ct*64 + cc*8] = pk;
    }
    __syncthreads();
  }
}

// ------------- K2/K6: 256^2-tile 8-phase bf16 MFMA GEMM ---------------------
// C[b][o][n] = A[o][c] * B[b][n][c]^T. A:[M][512], B:[b][4096][512], K-major.
// 512 thr / 8 waves (2 M x 4 N), per-wave 128x64 out, BK=64, 2 LDS slots.
// Per K-tile 4 phases: {ds_read quad || stage next half-tile; barrier;
// lgkmcnt0; setprio1; 16 MFMA; setprio0; barrier}. One vmcnt(0) per tile at
// P4 AFTER its MFMA (every staged load then has >=1 phase of flight lead).
// T2 swizzle: 16B-slot s stored at s^(row&7); gl_lds dest linear, global
// SOURCE pre-swizzled (rule #21), ds_read applies same XOR.
template<typename OUT_T, bool STATS>
__global__ __launch_bounds__(512, 2) void gemm_k(const u16* __restrict__ A,
                                                 const u16* __restrict__ Bm,
                                                 OUT_T* __restrict__ Cm, int M, int YT,
                                                 float* __restrict__ stats){
  __shared__ u16 lds[2][2][2][8192];   // [slot][mat A=0/B=1][half][128*64]
  int bi = blockIdx.x;
  int xcd = bi & 7, r2 = bi >> 3;
  int gi = r2 / YT, yy = r2 - gi*YT;
  int g  = gi*8 + xcd;
  int x  = g & 15, z = g >> 4;
  int o0 = yy*256, bn0 = x*256;
  int t = threadIdx.x;
  int lane = t & 63, wv = t >> 6;
  int wm = wv >> 2, wn = wv & 3, bh = wn >> 1;
  int fr = lane & 15, fg = lane >> 4;
  const u16* Ab = A + (size_t)o0*512;
  const u16* Bb = Bm + ((size_t)z*NS + bn0)*512;
  int rlo  = lane >> 3;                                  // row bits from lane
  int colx = ((lane & 7) ^ (lane >> 3 & 7)) << 3;        // pre-swizzled src col

  f32x4 acc[8][4];
  #pragma unroll
  for (int i=0;i<8;++i)
    #pragma unroll
    for (int j=0;j<4;++j) acc[i][j] = (f32x4){0.f,0.f,0.f,0.f};
  s16x8 afrag[4][2];        // current m-half: 4 m-frags x 2 k-slices
  s16x8 bfrag[2][2][2];     // both n-quads kept: [nq][nr][ks]

  auto stage = [&](int slot, int mat, int h, int kt){
    const u16* G = mat ? Bb : Ab;
    #pragma unroll
    for (int it=0; it<2; ++it){
      int u = wv*2 + it;
      int r = u*8 + rlo;
      gl_lds16(G + (size_t)(h*128 + r)*512 + kt + colx,
               &lds[slot][mat][h][u*512]);
    }
  };
  auto lda = [&](int slot, int mq){
    #pragma unroll
    for (int mr=0; mr<4; ++mr)
      #pragma unroll
      for (int ks=0; ks<2; ++ks){
        int r = (mq*4+mr)*16 + fr;
        int c = ((ks*4+fg) ^ (r&7)) << 3;
        afrag[mr][ks] = *(const s16x8*)&lds[slot][0][wm][r*64 + c];
      }
  };
  auto ldb = [&](int slot, int nq){
    #pragma unroll
    for (int nr=0; nr<2; ++nr)
      #pragma unroll
      for (int ks=0; ks<2; ++ks){
        int r = (wn&1)*64 + (nq*2+nr)*16 + fr;
        int c = ((ks*4+fg) ^ (r&7)) << 3;
        bfrag[nq][nr][ks] = *(const s16x8*)&lds[slot][1][bh][r*64 + c];
      }
  };
  auto mm = [&](int mq, int nq){
    #pragma unroll
    for (int mr=0;mr<4;++mr)
      #pragma unroll
      for (int nr=0;nr<2;++nr)
        #pragma unroll
        for (int ks=0;ks<2;++ks)
          acc[mq*4+mr][nq*2+nr] = __builtin_amdgcn_mfma_f32_16x16x32_bf16(
              afrag[mr][ks], bfrag[nq][nr][ks], acc[mq*4+mr][nq*2+nr], 0,0,0);
  };

  // prologue: T0 -> slot 0 (B first: longest lead for HBM-cold stream)
  stage(0,1,0,0); stage(0,1,1,0); stage(0,0,0,0); stage(0,0,1,0);
  VM0; SBAR; SCHED;

  for (int kt8 = 0; kt8 < 8; ++kt8){
    int slot = kt8 & 1, ns = slot ^ 1, ktn = (kt8+1)*64;
    bool F = kt8 < 7;
    // P1: quad (m0,n0)
    lda(slot,0); ldb(slot,0);
    if (F){ stage(ns,1,0,ktn); stage(ns,1,1,ktn); }
    SBAR; LGKM0; SCHED;
    __builtin_amdgcn_s_setprio(1); mm(0,0); __builtin_amdgcn_s_setprio(0);
    SBAR; SCHED;
    // P2: quad (m0,n1)
    ldb(slot,1);
    if (F) stage(ns,0,0,ktn);
    SBAR; LGKM0; SCHED;
    __builtin_amdgcn_s_setprio(1); mm(0,1); __builtin_amdgcn_s_setprio(0);
    SBAR; SCHED;
    // P3: quad (m1,n1)
    lda(slot,1);
    if (F) stage(ns,0,1,ktn);
    SBAR; LGKM0; SCHED;
    __builtin_amdgcn_s_setprio(1); mm(1,1); __builtin_amdgcn_s_setprio(0);
    SBAR; SCHED;
    // P4: quad (m1,n0) from regs; drain AFTER MFMA (loads keep >=1 phase lead)
    __builtin_amdgcn_s_setprio(1); mm(1,0); __builtin_amdgcn_s_setprio(0);
    if (F) VM0;
    SBAR; SCHED;
  }

  size_t cb = (size_t)z * M * NS;
  #pragma unroll
  for (int mi=0;mi<8;++mi)
    #pragma unroll
    for (int nj=0;nj<4;++nj){
      int row = o0 + wm*128 + mi*16 + fg*4;
      int col = bn0 + wn*64 + nj*16 + fr;
      #pragma unroll
      for (int r=0;r<4;++r)
        store_c(&Cm[cb + (size_t)(row+r)*NS + col], acc[mi][nj][r]);
    }

  if constexpr (STATS){
    // channel-partial (s1,s2) per n over this block's 256 o-rows
    float s1[4], s2[4];
    #pragma unroll
    for (int nj=0;nj<4;++nj){
      float a=0.f, b2=0.f;
      #pragma unroll
      for (int mi=0;mi<8;++mi)
        #pragma unroll
        for (int r=0;r<4;++r){ float v = acc[mi][nj][r]; a += v; b2 += v*v; }
      s1[nj]=a; s2[nj]=b2;
    }
    #pragma unroll
    for (int off=16; off<64; off<<=1)
      #pragma unroll
      for (int nj=0;nj<4;++nj){
        s1[nj] += __shfl_xor(s1[nj], off, 64);
        s2[nj] += __shfl_xor(s2[nj], off, 64);
      }
    float* red = (float*)&lds[0][0][0][0];   // loop done; LDS free
    if (fg == 0){
      #pragma unroll
      for (int nj=0;nj<4;++nj){
        red[(wn*2+wm)*64 + nj*16 + fr]        = s1[nj];
        red[512 + (wn*2+wm)*64 + nj*16 + fr]  = s2[nj];
      }
    }
    SBAR;
    if (t < 256){
      int wq = t >> 6, c = t & 63;
      float v1 = red[(wq*2+0)*64 + c] + red[(wq*2+1)*64 + c];
      float v2 = red[512+(wq*2+0)*64 + c] + red[512+(wq*2+1)*64 + c];
      int n = bn0 + wq*64 + c;
      size_t sb = ((size_t)(z*2 + yy)*2)*NS;
      stats[sb + n]      = v1;
      stats[sb + NS + n] = v2;
    }
  }
}

// ---------------- K3: k-softmax stats (max & sumexp over n) per (b, row) ----
__global__ __launch_bounds__(256) void kstats_k(const u16* __restrict__ qkv,
                                                float* __restrict__ kM, float* __restrict__ kS){
  int orr = blockIdx.x, b = blockIdx.y, t = threadIdx.x;
  const u16* kr = qkv + ((size_t)(b*1536 + 512 + orr))*NS + t*16;
  u16x8 va = *(const u16x8*)kr;
  u16x8 vb = *(const u16x8*)(kr + 8);
  float v[16];
  #pragma unroll
  for (int i=0;i<8;++i){ v[i] = bf2f(va[i]); v[8+i] = bf2f(vb[i]); }
  float m = v[0];
  #pragma unroll
  for (int i=1;i<16;++i) m = fmaxf(m, v[i]);
  #pragma unroll
  for (int off=32; off; off>>=1) m = fmaxf(m, __shfl_xor(m, off, 64));
  __shared__ float wm[4], wsum[4];
  if ((t&63)==0) wm[t>>6] = m;
  __syncthreads();
  m = fmaxf(fmaxf(wm[0],wm[1]), fmaxf(wm[2],wm[3]));
  float s = 0.f;
  #pragma unroll
  for (int i=0;i<16;++i) s += __expf(v[i]-m);
  #pragma unroll
  for (int off=32; off; off>>=1) s += __shfl_xor(s, off, 64);
  if ((t&63)==0) wsum[t>>6] = s;
  __syncthreads();
  if (t==0){ kM[b*512+orr] = m; kS[b*512+orr] = wsum[0]+wsum[1]+wsum[2]+wsum[3]; }
}

// ------- K4: context partials via MFMA: ctx[d][e] = sum_n ek'[d][n]*v[e][n] -
__global__ __launch_bounds__(256) void ctxpart_k(const u16* __restrict__ qkv,
                                                 const float* __restrict__ kM,
                                                 const float* __restrict__ kS,
                                                 float* __restrict__ part){
  int chunk = blockIdx.x, bh = blockIdx.y;
  int b = bh >> 3, h = bh & 7;
  int t = threadIdx.x;
  int lane = t & 63, wv = t >> 6;
  int fr = lane & 15, fg = lane >> 4;
  __shared__ u16 KT[64*128];
  __shared__ u16 VT[64*128];
  __shared__ float invn_s[128];
  __shared__ float mh[64], sh[64];
  if (t < 64){
    mh[t] = kM[b*512 + h*64 + t];
    sh[t] = 1.0f / (kS[b*512 + h*64 + t] * 4096.0f);
  }
  const u16* kb = qkv + ((size_t)(b*1536 + 512  + h*64))*NS;
  const u16* vb = qkv + ((size_t)(b*1536 + 1024 + h*64))*NS;
  int d = t >> 2, q = t & 3;

  f32x4 acc[4][4];
  #pragma unroll
  for (int i=0;i<4;++i)
    #pragma unroll
    for (int j=0;j<4;++j) acc[i][j] = (f32x4){0.f,0.f,0.f,0.f};

  for (int nt = 0; nt < 4; ++nt){
    int n0 = chunk*512 + nt*128;
    if (nt) __syncthreads();
    u16x8 kreg[4];
    #pragma unroll
    for (int s = 0; s < 4; ++s){
      int c0 = q*32 + s*8;
      u16x8 vv = *(const u16x8*)&vb[(size_t)d*NS + n0 + c0];
      *(u16x8*)&VT[d*128 + (c0 ^ ((d&7)<<3))] = vv;
      kreg[s] = *(const u16x8*)&kb[(size_t)d*NS + n0 + c0];
    }
    __syncthreads();
    if (t < 128){
      float ss = 0.f;
      #pragma unroll
      for (int e = 0; e < 64; ++e){
        float xv = bf2f(VT[e*128 + (t ^ ((e&7)<<3))]);
        ss += xv*xv;
      }
      invn_s[t] = rsqrtf(ss);
    }
    __syncthreads();
    float mm_ = mh[d], sc = sh[d];
    #pragma unroll
    for (int s = 0; s < 4; ++s){
      int c0 = q*32 + s*8;
      u16x8 kk = kreg[s];
      u16x8 ek;
      #pragma unroll
      for (int j = 0; j < 8; ++j)
        ek[j] = f2bf(__expf(bf2f(kk[j]) - mm_) * sc * invn_s[c0 + j]);
      *(u16x8*)&KT[d*128 + (c0 ^ ((d&7)<<3))] = ek;
    }
    __syncthreads();
    int kc = wv*32 + fg*8;
    s16x8 af[4], bfr[4];
    #pragma unroll
    for (int i=0;i<4;++i){
      int ra = i*16 + fr;
      af[i]  = *(const s16x8*)&KT[ra*128 + (kc ^ ((ra&7)<<3))];
      bfr[i] = *(const s16x8*)&VT[ra*128 + (kc ^ ((ra&7)<<3))];
    }
    #pragma unroll
    for (int i=0;i<4;++i)
      #pragma unroll
      for (int j=0;j<4;++j)
        acc[i][j] = __builtin_amdgcn_mfma_f32_16x16x32_bf16(af[i], bfr[j], acc[i][j], 0,0,0);
  }

  float* buf0 = (float*)KT;
  float* buf1 = (float*)VT;
  auto dump = [&](float* bf){
    #pragma unroll
    for (int i=0;i<4;++i)
      #pragma unroll
      for (int j=0;j<4;++j)
        #pragma unroll
        for (int r=0;r<4;++r) bf[((i*4+j)*4+r)*64 + lane] = acc[i][j][r];
  };
  auto addin = [&](float* bf){
    #pragma unroll
    for (int i=0;i<4;++i)
      #pragma unroll
      for (int j=0;j<4;++j)
        #pragma unroll
        for (int r=0;r<4;++r) acc[i][j][r] += bf[((i*4+j)*4+r)*64 + lane];
  };
  __syncthreads();
  if (wv==1) dump(buf0);
  if (wv==3) dump(buf1);
  __syncthreads();
  if (wv==0) addin(buf0);
  if (wv==2) addin(buf1);
  __syncthreads();
  if (wv==2) dump(buf0);
  __syncthreads();
  if (wv==0){
    addin(buf0);
    float* pp = part + ((size_t)bh*8 + chunk)*4096;
    #pragma unroll
    for (int i=0;i<4;++i)
      #pragma unroll
      for (int j=0;j<4;++j)
        #pragma unroll
        for (int r=0;r<4;++r)
          pp[(i*16+fg*4+r)*64 + j*16+fr] = acc[i][j][r];
  }
}

// ---------------- K4b: reduce 8 partials -> ctx[bh][64*64] -----------------
__global__ void ctxred_k(const float* __restrict__ part, float* __restrict__ ctx){
  int bh = blockIdx.x, t = threadIdx.x;
  #pragma unroll
  for (int i=0;i<16;++i){
    int idx = t + i*256;
    float s = 0.f;
    #pragma unroll
    for (int ch=0; ch<8; ++ch) s += part[((size_t)bh*8 + ch)*4096 + idx];
    ctx[(size_t)bh*4096 + idx] = s;
  }
}

// ------- K5: out = softmax_feat(q)*scale @ ctx  via MFMA, GELU, gT[b][n][c] -
__global__ __launch_bounds__(256) void attnout_k(const u16* __restrict__ qkv,
                                                 const float* __restrict__ ctx,
                                                 u16* __restrict__ gT){
  int bh = blockIdx.y;
  int b = bh >> 3, h = bh & 7;
  int n0 = blockIdx.x * 256;
  int t = threadIdx.x;
  int lane = t & 63, wv = t >> 6;
  int fr = lane & 15, fg = lane >> 4;
  __shared__ u16 P[256][72];
  __shared__ u16 cT[64][72];

  const float* cs = ctx + (size_t)bh*4096;
  #pragma unroll
  for (int i=0;i<16;++i){
    int idx = i*256 + t;
    int d = idx >> 6, e = idx & 63;
    cT[e][d] = f2bf(cs[idx]);
  }

  const u16* qb = qkv + ((size_t)(b*1536 + h*64))*NS + n0 + t;
  float p[64];
  #pragma unroll
  for (int d=0; d<64; ++d) p[d] = bf2f(qb[(size_t)d*NS]);
  float m = p[0];
  #pragma unroll
  for (int d=1; d<64; ++d) m = fmaxf(m, p[d]);
  float s = 0.f;
  #pragma unroll
  for (int d=0; d<64; ++d){ p[d] = __expf(p[d]-m); s += p[d]; }
  float inv = 0.125f / s;
  #pragma unroll
  for (int d0=0; d0<8; ++d0){
    u16x8 pk;
    #pragma unroll
    for (int j=0;j<8;++j) pk[j] = f2bf(p[d0*8+j] * inv);
    *(u16x8*)&P[t][d0*8] = pk;
  }
  __syncthreads();

  f32x4 acc[4][4];
  #pragma unroll
  for (int i=0;i<4;++i)
    #pragma unroll
    for (int j=0;j<4;++j) acc[i][j] = (f32x4){0.f,0.f,0.f,0.f};
  #pragma unroll
  for (int k=0; k<2; ++k){
    s16x8 af[4], bfr[4];
    #pragma unroll
    for (int i=0;i<4;++i){
      af[i]  = *(const s16x8*)&P[wv*64 + i*16 + fr][k*32 + fg*8];
      bfr[i] = *(const s16x8*)&cT[i*16 + fr][k*32 + fg*8];
    }
    #pragma unroll
    for (int i=0;i<4;++i)
      #pragma unroll
      for (int j=0;j<4;++j)
        acc[i][j] = __builtin_amdgcn_mfma_f32_16x16x32_bf16(af[i], bfr[j], acc[i][j], 0,0,0);
  }

  #pragma unroll
  for (int i=0;i<4;++i)
    #pragma unroll
    for (int j=0;j<4;++j)
      #pragma unroll
      for (int r=0;r<4;++r)
        P[wv*64 + i*16 + fg*4 + r][j*16 + fr] = f2bf(gelu_f(acc[i][j][r]));

  int sub = lane >> 4, e4 = (lane & 15) * 4;
  #pragma unroll
  for (int it=0; it<16; ++it){
    int row = wv*64 + it*4 + sub;
    *(u16x4*)&gT[((size_t)b*NS + n0 + row)*CD + h*64 + e4] = *(u16x4*)&P[row][e4];
  }
}

// -------- K7: final ChanLN (stats precomputed in gemm2), single pass -------
__global__ __launch_bounds__(256) void ln2_k(const float* __restrict__ y,
                                             const float* __restrict__ stats,
                                             const float* __restrict__ g2,
                                             float* __restrict__ out){
  int b = blockIdx.y, n0 = blockIdx.x * 128;
  int t = threadIdx.x;
  int nl = (t & 63) * 2, cg = t >> 6;
  float s1a=0.f, s1b=0.f, s2a=0.f, s2b=0.f;
  #pragma unroll
  for (int ob=0; ob<2; ++ob){
    size_t sb = ((size_t)(b*2 + ob)*2)*NS + n0 + nl;
    s1a += stats[sb];      s1b += stats[sb+1];
    s2a += stats[sb+NS];   s2b += stats[sb+NS+1];
  }
  float mna = s1a*(1.f/512.f), mnb = s1b*(1.f/512.f);
  float ra = rsqrtf(s2a*(1.f/512.f) - mna*mna + 1e-5f);
  float rb = rsqrtf(s2b*(1.f/512.f) - mnb*mnb + 1e-5f);
  const float* yb = y + (size_t)b*CD*NS + n0 + nl;
  float* ob_ = out + (size_t)b*CD*NS + n0 + nl;
  for (int c = cg*128; c < cg*128 + 128; ++c){
    f32x2 v = *(const f32x2*)&yb[(size_t)c*NS];
    float g = g2[c];
    f32x2 o;
    o[0] = (v[0]-mna)*ra*g;
    o[1] = (v[1]-mnb)*rb*g;
    *(f32x2*)&ob_[(size_t)c*NS] = o;
  }
}

extern "C" void kernel_launch(void* const* d_in, const int* in_sizes, int n_in,
                              void* d_out, int out_size, void* d_ws, size_t ws_size,
                              hipStream_t stream) {
  const float* fmap = (const float*)d_in[0];
  const float* g1   = (const float*)d_in[1];
  const float* wqkv = (const float*)d_in[2];
  const float* wout = (const float*)d_in[3];
  const float* g2   = (const float*)d_in[4];
  float* out = (float*)d_out;

  char* ws = (char*)d_ws;
  size_t off = 0;
  auto alloc = [&](size_t bytes) -> void* {
    void* p = ws + off;
    off += (bytes + 255) & ~(size_t)255;
    return p;
  };
  u16*   qkv  = (u16*)alloc((size_t)16*1536*4096*2);   // reused as y fp32
  float* y    = (float*)qkv;
  u16*   xlnT = (u16*)alloc((size_t)16*4096*512*2);    // reused as gT
  u16*   gT   = xlnT;
  float* kM    = (float*)alloc((size_t)16*512*4);
  float* kS    = (float*)alloc((size_t)16*512*4);
  float* part  = (float*)alloc((size_t)128*8*4096*4);
  float* ctx   = (float*)alloc((size_t)128*4096*4);
  float* stats = (float*)alloc((size_t)16*2*2*4096*4);
  u16*   w1b  = (u16*)alloc((size_t)1536*512*2);
  u16*   w2b  = (u16*)alloc((size_t)512*512*2);
  if (off > ws_size) return;

  prep_w_k<<<4096, 256, 0, stream>>>(wqkv, g1, wout, w1b, w2b);
  ln1t_k<<<dim3(64,16), 256, 0, stream>>>(fmap, xlnT);
  gemm_k<u16,false><<<1536, 512, 0, stream>>>(w1b, xlnT, qkv, 1536, 6, nullptr);
  kstats_k<<<dim3(512,16), 256, 0, stream>>>(qkv, kM, kS);
  ctxpart_k<<<dim3(8,128), 256, 0, stream>>>(qkv, kM, kS, part);
  ctxred_k<<<128, 256, 0, stream>>>(part, ctx);
  attnout_k<<<dim3(16,128), 256, 0, stream>>>(qkv, ctx, gT);
  gemm_k<float,true><<<512, 512, 0, stream>>>(w2b, gT, y, 512, 2, stats);
  ln2_k<<<dim3(32,16), 256, 0, stream>>>(y, stats, g2, out);
}

// Round 5
// 417.077 us; speedup vs baseline: 5.8930x; 1.0451x over previous
//
#include <hip/hip_runtime.h>

typedef unsigned short u16;
typedef __attribute__((ext_vector_type(2))) float f32x2;
typedef __attribute__((ext_vector_type(4))) float f32x4;
typedef __attribute__((ext_vector_type(8))) short s16x8;
typedef __attribute__((ext_vector_type(8))) u16 u16x8;
typedef __attribute__((ext_vector_type(4))) u16 u16x4;

#define NB 16
#define CD 512
#define NS 4096
#define NHD 8

#define SBAR  __builtin_amdgcn_s_barrier()
#define SCHED __builtin_amdgcn_sched_barrier(0)
#define LGKM0 asm volatile("s_waitcnt lgkmcnt(0)" ::: "memory")
#define VM0   asm volatile("s_waitcnt vmcnt(0)" ::: "memory")

__device__ __forceinline__ float bf2f(u16 u){
  union { unsigned int i; float f; } z; z.i = ((unsigned int)u) << 16; return z.f;
}
__device__ __forceinline__ u16 f2bf(float f){
  union { float f; unsigned int i; } z; z.f = f;
  unsigned int i = z.i;
  return (u16)((i + 0x7fffu + ((i >> 16) & 1u)) >> 16);
}
__device__ __forceinline__ float gelu_f(float x){
  return 0.5f * x * (1.0f + erff(x * 0.70710678118654752440f));
}
__device__ __forceinline__ void gl_lds16(const u16* g, u16* l){
  __builtin_amdgcn_global_load_lds((const __attribute__((address_space(1))) void*)(g),
                                   (__attribute__((address_space(3))) void*)(l), 16, 0, 0);
}

__device__ __forceinline__ void store_c(u16* p, float v){ *p = f2bf(v); }
__device__ __forceinline__ void store_c(float* p, float v){ *p = v; }

// ---------------- K0: weights -> bf16 (g1 folded into w_qkv) ----------------
__global__ void prep_w_k(const float* __restrict__ wqkv, const float* __restrict__ g1,
                         const float* __restrict__ wout, u16* __restrict__ w1b,
                         u16* __restrict__ w2b){
  int i = blockIdx.x * 256 + threadIdx.x;
  if (i < 1536*512) {
    w1b[i] = f2bf(wqkv[i] * g1[i & 511]);
  } else {
    int j = i - 1536*512;
    w2b[j] = f2bf(wout[j]);
  }
}

// ------- K1: ChanLN over c, single global read via big-LDS staging ---------
// Block: 512 thr, tile = 512 c x 32 n fp32 staged in LDS (80.6 KB, 2 blk/CU).
// Stats computed during the load (per-thread column partials + shfl + LDS).
// Then normalize + transpose via small bf16 tile, write xlnT[b][n][c].
__global__ __launch_bounds__(512) void ln1t_k(const float* __restrict__ fmap,
                                              u16* __restrict__ xlnT){
  int b = blockIdx.y, n0 = blockIdx.x * 32;
  int t = threadIdx.x;
  int lane = t & 63, wv = t >> 6;
  __shared__ float Lb[512][36];
  __shared__ u16 Tt[64][36];
  __shared__ float red1[8][8][4], red2[8][8][4];
  __shared__ float mean_s[32], rstd_s[32];

  int ng = t & 7;                // column group (cols ng*4..+3), const per thread
  float s1[4] = {0,0,0,0}, s2[4] = {0,0,0,0};
  const float* fb = fmap + ((size_t)b*CD)*NS + n0 + ng*4;
  #pragma unroll
  for (int it = 0; it < 8; ++it){
    int q = it*512 + t;
    int c = q >> 3;
    f32x4 v = *(const f32x4*)&fb[(size_t)c*NS];
    *(f32x4*)&Lb[c][ng*4] = v;
    #pragma unroll
    for (int j = 0; j < 4; ++j){ s1[j] += v[j]; s2[j] += v[j]*v[j]; }
  }
  // reduce over the 8 same-group lanes in this wave (stride 8)
  #pragma unroll
  for (int off = 8; off < 64; off <<= 1)
    #pragma unroll
    for (int j = 0; j < 4; ++j){
      s1[j] += __shfl_xor(s1[j], off, 64);
      s2[j] += __shfl_xor(s2[j], off, 64);
    }
  if (lane < 8){
    #pragma unroll
    for (int j = 0; j < 4; ++j){ red1[wv][lane][j] = s1[j]; red2[wv][lane][j] = s2[j]; }
  }
  __syncthreads();
  if (t < 32){
    int g = t >> 2, j = t & 3;
    float a = 0.f, bq = 0.f;
    #pragma unroll
    for (int w = 0; w < 8; ++w){ a += red1[w][g][j]; bq += red2[w][g][j]; }
    float mn = a * (1.f/512.f);
    float var = bq * (1.f/512.f) - mn*mn;
    mean_s[t] = mn; rstd_s[t] = rsqrtf(var + 1e-5f);
  }
  __syncthreads();

  for (int ct = 0; ct < 8; ++ct){
    {
      int cl = t >> 3, n4 = (t & 7) * 4;
      f32x4 v = *(const f32x4*)&Lb[ct*64 + cl][n4];
      u16x4 pk;
      #pragma unroll
      for (int j = 0; j < 4; ++j)
        pk[j] = f2bf((v[j] - mean_s[n4+j]) * rstd_s[n4+j]);
      *(u16x4*)&Tt[cl][n4] = pk;
    }
    __syncthreads();
    {
      int nr = t >> 4, c4 = t & 15;
      u16x4 w;
      #pragma unroll
      for (int j = 0; j < 4; ++j) w[j] = Tt[c4*4 + j][nr];
      *(u16x4*)&xlnT[((size_t)b*NS + n0 + nr)*CD + ct*64 + c4*4] = w;
    }
    __syncthreads();
  }
}

// ------------- K2/K6: 256^2-tile 8-phase bf16 MFMA GEMM ---------------------
// C[b][o][n] = A[o][c] * B[b][n][c]^T. A:[M][512], B:[b][4096][512], K-major.
// 512 thr / 8 waves (2 M x 4 N), per-wave 128x64 out, BK=64, 2 LDS slots.
// All 4 next-tile half-tiles staged at P1 (3-4 phases of flight lead);
// single vmcnt(0) drain at P4 after its MFMA. T2 swizzle rule-#21 correct.
template<typename OUT_T, bool STATS>
__global__ __launch_bounds__(512, 2) void gemm_k(const u16* __restrict__ A,
                                                 const u16* __restrict__ Bm,
                                                 OUT_T* __restrict__ Cm, int M, int YT,
                                                 float* __restrict__ stats){
  __shared__ u16 lds[2][2][2][8192];   // [slot][mat A=0/B=1][half][128*64]
  int bi = blockIdx.x;
  int xcd = bi & 7, r2 = bi >> 3;
  int gi = r2 / YT, yy = r2 - gi*YT;
  int g  = gi*8 + xcd;
  int x  = g & 15, z = g >> 4;
  int o0 = yy*256, bn0 = x*256;
  int t = threadIdx.x;
  int lane = t & 63, wv = t >> 6;
  int wm = wv >> 2, wn = wv & 3, bh = wn >> 1;
  int fr = lane & 15, fg = lane >> 4;
  const u16* Ab = A + (size_t)o0*512;
  const u16* Bb = Bm + ((size_t)z*NS + bn0)*512;
  int rlo  = lane >> 3;                                  // row bits from lane
  int colx = ((lane & 7) ^ (lane >> 3 & 7)) << 3;        // pre-swizzled src col

  f32x4 acc[8][4];
  #pragma unroll
  for (int i=0;i<8;++i)
    #pragma unroll
    for (int j=0;j<4;++j) acc[i][j] = (f32x4){0.f,0.f,0.f,0.f};
  s16x8 afrag[4][2];
  s16x8 bfrag[2][2][2];

  auto stage = [&](int slot, int mat, int h, int kt){
    const u16* G = mat ? Bb : Ab;
    #pragma unroll
    for (int it=0; it<2; ++it){
      int u = wv*2 + it;
      int r = u*8 + rlo;
      gl_lds16(G + (size_t)(h*128 + r)*512 + kt + colx,
               &lds[slot][mat][h][u*512]);
    }
  };
  auto lda = [&](int slot, int mq){
    #pragma unroll
    for (int mr=0; mr<4; ++mr)
      #pragma unroll
      for (int ks=0; ks<2; ++ks){
        int r = (mq*4+mr)*16 + fr;
        int c = ((ks*4+fg) ^ (r&7)) << 3;
        afrag[mr][ks] = *(const s16x8*)&lds[slot][0][wm][r*64 + c];
      }
  };
  auto ldb = [&](int slot, int nq){
    #pragma unroll
    for (int nr=0; nr<2; ++nr)
      #pragma unroll
      for (int ks=0; ks<2; ++ks){
        int r = (wn&1)*64 + (nq*2+nr)*16 + fr;
        int c = ((ks*4+fg) ^ (r&7)) << 3;
        bfrag[nq][nr][ks] = *(const s16x8*)&lds[slot][1][bh][r*64 + c];
      }
  };
  auto mm = [&](int mq, int nq){
    #pragma unroll
    for (int mr=0;mr<4;++mr)
      #pragma unroll
      for (int nr=0;nr<2;++nr)
        #pragma unroll
        for (int ks=0;ks<2;++ks)
          acc[mq*4+mr][nq*2+nr] = __builtin_amdgcn_mfma_f32_16x16x32_bf16(
              afrag[mr][ks], bfrag[nq][nr][ks], acc[mq*4+mr][nq*2+nr], 0,0,0);
  };

  // prologue: T0 -> slot 0
  stage(0,1,0,0); stage(0,1,1,0); stage(0,0,0,0); stage(0,0,1,0);
  VM0; SBAR; SCHED;

  for (int kt8 = 0; kt8 < 8; ++kt8){
    int slot = kt8 & 1, ns = slot ^ 1, ktn = (kt8+1)*64;
    bool F = kt8 < 7;
    // P1: quad (m0,n0); ALL next-tile staging issued here (max flight lead)
    lda(slot,0); ldb(slot,0);
    if (F){ stage(ns,1,0,ktn); stage(ns,1,1,ktn); stage(ns,0,0,ktn); stage(ns,0,1,ktn); }
    SBAR; LGKM0; SCHED;
    __builtin_amdgcn_s_setprio(1); mm(0,0); __builtin_amdgcn_s_setprio(0);
    SBAR; SCHED;
    // P2: quad (m0,n1)
    ldb(slot,1);
    SBAR; LGKM0; SCHED;
    __builtin_amdgcn_s_setprio(1); mm(0,1); __builtin_amdgcn_s_setprio(0);
    SBAR; SCHED;
    // P3: quad (m1,n1)
    lda(slot,1);
    SBAR; LGKM0; SCHED;
    __builtin_amdgcn_s_setprio(1); mm(1,1); __builtin_amdgcn_s_setprio(0);
    SBAR; SCHED;
    // P4: quad (m1,n0) from regs; drain AFTER MFMA (loads have 3-4 phase lead)
    __builtin_amdgcn_s_setprio(1); mm(1,0); __builtin_amdgcn_s_setprio(0);
    if (F) VM0;
    SBAR; SCHED;
  }

  size_t cb = (size_t)z * M * NS;
  #pragma unroll
  for (int mi=0;mi<8;++mi)
    #pragma unroll
    for (int nj=0;nj<4;++nj){
      int row = o0 + wm*128 + mi*16 + fg*4;
      int col = bn0 + wn*64 + nj*16 + fr;
      #pragma unroll
      for (int r=0;r<4;++r)
        store_c(&Cm[cb + (size_t)(row+r)*NS + col], acc[mi][nj][r]);
    }

  if constexpr (STATS){
    float s1[4], s2[4];
    #pragma unroll
    for (int nj=0;nj<4;++nj){
      float a=0.f, b2=0.f;
      #pragma unroll
      for (int mi=0;mi<8;++mi)
        #pragma unroll
        for (int r=0;r<4;++r){ float v = acc[mi][nj][r]; a += v; b2 += v*v; }
      s1[nj]=a; s2[nj]=b2;
    }
    #pragma unroll
    for (int off=16; off<64; off<<=1)
      #pragma unroll
      for (int nj=0;nj<4;++nj){
        s1[nj] += __shfl_xor(s1[nj], off, 64);
        s2[nj] += __shfl_xor(s2[nj], off, 64);
      }
    float* red = (float*)&lds[0][0][0][0];
    if (fg == 0){
      #pragma unroll
      for (int nj=0;nj<4;++nj){
        red[(wn*2+wm)*64 + nj*16 + fr]        = s1[nj];
        red[512 + (wn*2+wm)*64 + nj*16 + fr]  = s2[nj];
      }
    }
    SBAR;
    if (t < 256){
      int wq = t >> 6, c = t & 63;
      float v1 = red[(wq*2+0)*64 + c] + red[(wq*2+1)*64 + c];
      float v2 = red[512+(wq*2+0)*64 + c] + red[512+(wq*2+1)*64 + c];
      int n = bn0 + wq*64 + c;
      size_t sb = ((size_t)(z*2 + yy)*2)*NS;
      stats[sb + n]      = v1;
      stats[sb + NS + n] = v2;
    }
  }
}

// ------- K4: context partials (online k-softmax, local max per chunk) ------
// part_c[d][e] = sum_{n in chunk} e^{k-m_c} * invn[n] * v[e][n]; also writes
// (m_c, S_c) per (bh,chunk,d) for the ctxred merge. No global stats pass.
__global__ __launch_bounds__(256) void ctxpart_k(const u16* __restrict__ qkv,
                                                 float* __restrict__ part,
                                                 float* __restrict__ mS){
  int chunk = blockIdx.x, bh = blockIdx.y;
  int b = bh >> 3, h = bh & 7;
  int t = threadIdx.x;
  int lane = t & 63, wv = t >> 6;
  int fr = lane & 15, fg = lane >> 4;
  __shared__ u16 KT[64*128];
  __shared__ u16 VT[64*128];
  __shared__ float invn_s[128];
  const u16* kb = qkv + ((size_t)(b*1536 + 512  + h*64))*NS;
  const u16* vb = qkv + ((size_t)(b*1536 + 1024 + h*64))*NS;
  int d = t >> 2, q = t & 3;

  // pre-sweep: per-chunk local max for row d over its 512 cols
  float mloc = -3.0e38f;
  #pragma unroll
  for (int nt = 0; nt < 4; ++nt)
    #pragma unroll
    for (int s = 0; s < 4; ++s){
      u16x8 kk = *(const u16x8*)&kb[(size_t)d*NS + chunk*512 + nt*128 + q*32 + s*8];
      #pragma unroll
      for (int j = 0; j < 8; ++j) mloc = fmaxf(mloc, bf2f(kk[j]));
    }
  mloc = fmaxf(mloc, __shfl_xor(mloc, 1, 64));
  mloc = fmaxf(mloc, __shfl_xor(mloc, 2, 64));
  float sloc = 0.f;

  f32x4 acc[4][4];
  #pragma unroll
  for (int i=0;i<4;++i)
    #pragma unroll
    for (int j=0;j<4;++j) acc[i][j] = (f32x4){0.f,0.f,0.f,0.f};

  for (int nt = 0; nt < 4; ++nt){
    int n0 = chunk*512 + nt*128;
    if (nt) __syncthreads();
    u16x8 kreg[4];
    #pragma unroll
    for (int s = 0; s < 4; ++s){
      int c0 = q*32 + s*8;
      u16x8 vv = *(const u16x8*)&vb[(size_t)d*NS + n0 + c0];
      *(u16x8*)&VT[d*128 + (c0 ^ ((d&7)<<3))] = vv;
      kreg[s] = *(const u16x8*)&kb[(size_t)d*NS + n0 + c0];
    }
    __syncthreads();
    if (t < 128){
      float ss = 0.f;
      #pragma unroll
      for (int e = 0; e < 64; ++e){
        float xv = bf2f(VT[e*128 + (t ^ ((e&7)<<3))]);
        ss += xv*xv;
      }
      invn_s[t] = rsqrtf(ss);
    }
    __syncthreads();
    #pragma unroll
    for (int s = 0; s < 4; ++s){
      int c0 = q*32 + s*8;
      u16x8 kk = kreg[s];
      u16x8 ek;
      #pragma unroll
      for (int j = 0; j < 8; ++j){
        float e = __expf(bf2f(kk[j]) - mloc);
        sloc += e;
        ek[j] = f2bf(e * invn_s[c0 + j]);
      }
      *(u16x8*)&KT[d*128 + (c0 ^ ((d&7)<<3))] = ek;
    }
    __syncthreads();
    int kc = wv*32 + fg*8;
    s16x8 af[4], bfr[4];
    #pragma unroll
    for (int i=0;i<4;++i){
      int ra = i*16 + fr;
      af[i]  = *(const s16x8*)&KT[ra*128 + (kc ^ ((ra&7)<<3))];
      bfr[i] = *(const s16x8*)&VT[ra*128 + (kc ^ ((ra&7)<<3))];
    }
    #pragma unroll
    for (int i=0;i<4;++i)
      #pragma unroll
      for (int j=0;j<4;++j)
        acc[i][j] = __builtin_amdgcn_mfma_f32_16x16x32_bf16(af[i], bfr[j], acc[i][j], 0,0,0);
  }

  // per-chunk softmax denominator (sum over all 512 cols of row d)
  sloc += __shfl_xor(sloc, 1, 64);
  sloc += __shfl_xor(sloc, 2, 64);
  if (q == 0){
    size_t mb = ((size_t)bh*8 + chunk)*128;
    mS[mb + d]      = mloc;
    mS[mb + 64 + d] = sloc;
  }

  // cross-wave reduce of the 64x64 C (waves hold disjoint-K partials)
  float* buf0 = (float*)KT;
  float* buf1 = (float*)VT;
  auto dump = [&](float* bf){
    #pragma unroll
    for (int i=0;i<4;++i)
      #pragma unroll
      for (int j=0;j<4;++j)
        #pragma unroll
        for (int r=0;r<4;++r) bf[((i*4+j)*4+r)*64 + lane] = acc[i][j][r];
  };
  auto addin = [&](float* bf){
    #pragma unroll
    for (int i=0;i<4;++i)
      #pragma unroll
      for (int j=0;j<4;++j)
        #pragma unroll
        for (int r=0;r<4;++r) acc[i][j][r] += bf[((i*4+j)*4+r)*64 + lane];
  };
  __syncthreads();
  if (wv==1) dump(buf0);
  if (wv==3) dump(buf1);
  __syncthreads();
  if (wv==0) addin(buf0);
  if (wv==2) addin(buf1);
  __syncthreads();
  if (wv==2) dump(buf0);
  __syncthreads();
  if (wv==0){
    addin(buf0);
    float* pp = part + ((size_t)bh*8 + chunk)*4096;
    #pragma unroll
    for (int i=0;i<4;++i)
      #pragma unroll
      for (int j=0;j<4;++j)
        #pragma unroll
        for (int r=0;r<4;++r)
          pp[(i*16+fg*4+r)*64 + j*16+fr] = acc[i][j][r];
  }
}

// ---- K4b: merge 8 chunk partials with online-softmax scales -> ctx --------
__global__ void ctxred_k(const float* __restrict__ part, const float* __restrict__ mS,
                         float* __restrict__ ctx){
  int bh = blockIdx.x, t = threadIdx.x;
  __shared__ float fs[8][64];
  if (t < 64){
    int d = t;
    float mc[8];
    float mx = -3.0e38f;
    #pragma unroll
    for (int c=0;c<8;++c){ mc[c] = mS[((size_t)bh*8 + c)*128 + d]; mx = fmaxf(mx, mc[c]); }
    float es[8]; float denom = 0.f;
    #pragma unroll
    for (int c=0;c<8;++c){
      es[c] = __expf(mc[c] - mx);
      denom += es[c] * mS[((size_t)bh*8 + c)*128 + 64 + d];
    }
    float inv = 1.0f / (denom * 4096.0f);
    #pragma unroll
    for (int c=0;c<8;++c) fs[c][d] = es[c] * inv;
  }
  __syncthreads();
  #pragma unroll
  for (int i=0;i<16;++i){
    int idx = t + i*256;
    int d = idx >> 6;
    float s = 0.f;
    #pragma unroll
    for (int ch=0; ch<8; ++ch) s += fs[ch][d] * part[((size_t)bh*8 + ch)*4096 + idx];
    ctx[(size_t)bh*4096 + idx] = s;
  }
}

// ------- K5: out = softmax_feat(q)*scale @ ctx  via MFMA, GELU, gT[b][n][c] -
__global__ __launch_bounds__(256) void attnout_k(const u16* __restrict__ qkv,
                                                 const float* __restrict__ ctx,
                                                 u16* __restrict__ gT){
  int bh = blockIdx.y;
  int b = bh >> 3, h = bh & 7;
  int n0 = blockIdx.x * 256;
  int t = threadIdx.x;
  int lane = t & 63, wv = t >> 6;
  int fr = lane & 15, fg = lane >> 4;
  __shared__ u16 P[256][72];
  __shared__ u16 cT[64][72];

  const float* cs = ctx + (size_t)bh*4096;
  #pragma unroll
  for (int i=0;i<16;++i){
    int idx = i*256 + t;
    int d = idx >> 6, e = idx & 63;
    cT[e][d] = f2bf(cs[idx]);
  }

  const u16* qb = qkv + ((size_t)(b*1536 + h*64))*NS + n0 + t;
  float p[64];
  #pragma unroll
  for (int d=0; d<64; ++d) p[d] = bf2f(qb[(size_t)d*NS]);
  float m = p[0];
  #pragma unroll
  for (int d=1; d<64; ++d) m = fmaxf(m, p[d]);
  float s = 0.f;
  #pragma unroll
  for (int d=0; d<64; ++d){ p[d] = __expf(p[d]-m); s += p[d]; }
  float inv = 0.125f / s;
  #pragma unroll
  for (int d0=0; d0<8; ++d0){
    u16x8 pk;
    #pragma unroll
    for (int j=0;j<8;++j) pk[j] = f2bf(p[d0*8+j] * inv);
    *(u16x8*)&P[t][d0*8] = pk;
  }
  __syncthreads();

  f32x4 acc[4][4];
  #pragma unroll
  for (int i=0;i<4;++i)
    #pragma unroll
    for (int j=0;j<4;++j) acc[i][j] = (f32x4){0.f,0.f,0.f,0.f};
  #pragma unroll
  for (int k=0; k<2; ++k){
    s16x8 af[4], bfr[4];
    #pragma unroll
    for (int i=0;i<4;++i){
      af[i]  = *(const s16x8*)&P[wv*64 + i*16 + fr][k*32 + fg*8];
      bfr[i] = *(const s16x8*)&cT[i*16 + fr][k*32 + fg*8];
    }
    #pragma unroll
    for (int i=0;i<4;++i)
      #pragma unroll
      for (int j=0;j<4;++j)
        acc[i][j] = __builtin_amdgcn_mfma_f32_16x16x32_bf16(af[i], bfr[j], acc[i][j], 0,0,0);
  }

  #pragma unroll
  for (int i=0;i<4;++i)
    #pragma unroll
    for (int j=0;j<4;++j)
      #pragma unroll
      for (int r=0;r<4;++r)
        P[wv*64 + i*16 + fg*4 + r][j*16 + fr] = f2bf(gelu_f(acc[i][j][r]));

  int sub = lane >> 4, e4 = (lane & 15) * 4;
  #pragma unroll
  for (int it=0; it<16; ++it){
    int row = wv*64 + it*4 + sub;
    *(u16x4*)&gT[((size_t)b*NS + n0 + row)*CD + h*64 + e4] = *(u16x4*)&P[row][e4];
  }
}

// -------- K7: final ChanLN (stats precomputed in gemm2), single pass -------
__global__ __launch_bounds__(256) void ln2_k(const float* __restrict__ y,
                                             const float* __restrict__ stats,
                                             const float* __restrict__ g2,
                                             float* __restrict__ out){
  int b = blockIdx.y, n0 = blockIdx.x * 128;
  int t = threadIdx.x;
  int nl = (t & 63) * 2, cg = t >> 6;
  float s1a=0.f, s1b=0.f, s2a=0.f, s2b=0.f;
  #pragma unroll
  for (int ob=0; ob<2; ++ob){
    size_t sb = ((size_t)(b*2 + ob)*2)*NS + n0 + nl;
    s1a += stats[sb];      s1b += stats[sb+1];
    s2a += stats[sb+NS];   s2b += stats[sb+NS+1];
  }
  float mna = s1a*(1.f/512.f), mnb = s1b*(1.f/512.f);
  float ra = rsqrtf(s2a*(1.f/512.f) - mna*mna + 1e-5f);
  float rb = rsqrtf(s2b*(1.f/512.f) - mnb*mnb + 1e-5f);
  const float* yb = y + (size_t)b*CD*NS + n0 + nl;
  float* ob_ = out + (size_t)b*CD*NS + n0 + nl;
  for (int c = cg*128; c < cg*128 + 128; ++c){
    f32x2 v = *(const f32x2*)&yb[(size_t)c*NS];
    float g = g2[c];
    f32x2 o;
    o[0] = (v[0]-mna)*ra*g;
    o[1] = (v[1]-mnb)*rb*g;
    *(f32x2*)&ob_[(size_t)c*NS] = o;
  }
}

extern "C" void kernel_launch(void* const* d_in, const int* in_sizes, int n_in,
                              void* d_out, int out_size, void* d_ws, size_t ws_size,
                              hipStream_t stream) {
  const float* fmap = (const float*)d_in[0];
  const float* g1   = (const float*)d_in[1];
  const float* wqkv = (const float*)d_in[2];
  const float* wout = (const float*)d_in[3];
  const float* g2   = (const float*)d_in[4];
  float* out = (float*)d_out;

  char* ws = (char*)d_ws;
  size_t off = 0;
  auto alloc = [&](size_t bytes) -> void* {
    void* p = ws + off;
    off += (bytes + 255) & ~(size_t)255;
    return p;
  };
  u16*   qkv  = (u16*)alloc((size_t)16*1536*4096*2);   // reused as y fp32
  float* y    = (float*)qkv;
  u16*   xlnT = (u16*)alloc((size_t)16*4096*512*2);    // reused as gT
  u16*   gT   = xlnT;
  float* part  = (float*)alloc((size_t)128*8*4096*4);
  float* mS    = (float*)alloc((size_t)128*8*128*4);
  float* ctx   = (float*)alloc((size_t)128*4096*4);
  float* stats = (float*)alloc((size_t)16*2*2*4096*4);
  u16*   w1b  = (u16*)alloc((size_t)1536*512*2);
  u16*   w2b  = (u16*)alloc((size_t)512*512*2);
  if (off > ws_size) return;

  prep_w_k<<<4096, 256, 0, stream>>>(wqkv, g1, wout, w1b, w2b);
  ln1t_k<<<dim3(128,16), 512, 0, stream>>>(fmap, xlnT);
  gemm_k<u16,false><<<1536, 512, 0, stream>>>(w1b, xlnT, qkv, 1536, 6, nullptr);
  ctxpart_k<<<dim3(8,128), 256, 0, stream>>>(qkv, part, mS);
  ctxred_k<<<128, 256, 0, stream>>>(part, mS, ctx);
  attnout_k<<<dim3(16,128), 256, 0, stream>>>(qkv, ctx, gT);
  gemm_k<float,true><<<512, 512, 0, stream>>>(w2b, gT, y, 512, 2, stats);
  ln2_k<<<dim3(32,16), 256, 0, stream>>>(y, stats, g2, out);
}

// Round 6
// 343.064 us; speedup vs baseline: 7.1644x; 1.2157x over previous
//
#include <hip/hip_runtime.h>

typedef unsigned short u16;
typedef __attribute__((ext_vector_type(2))) float f32x2;
typedef __attribute__((ext_vector_type(4))) float f32x4;
typedef __attribute__((ext_vector_type(8))) short s16x8;
typedef __attribute__((ext_vector_type(8))) u16 u16x8;
typedef __attribute__((ext_vector_type(4))) u16 u16x4;

#define NB 16
#define CD 512
#define NS 4096
#define NHD 8

#define SBAR  __builtin_amdgcn_s_barrier()
#define SCHED __builtin_amdgcn_sched_barrier(0)
#define LGKM0 asm volatile("s_waitcnt lgkmcnt(0)" ::: "memory")
#define PRIO1 __builtin_amdgcn_s_setprio(1)
#define PRIO0 __builtin_amdgcn_s_setprio(0)

__device__ __forceinline__ float bf2f(u16 u){
  union { unsigned int i; float f; } z; z.i = ((unsigned int)u) << 16; return z.f;
}
__device__ __forceinline__ u16 f2bf(float f){
  union { float f; unsigned int i; } z; z.f = f;
  unsigned int i = z.i;
  return (u16)((i + 0x7fffu + ((i >> 16) & 1u)) >> 16);
}
__device__ __forceinline__ float gelu_f(float x){
  return 0.5f * x * (1.0f + erff(x * 0.70710678118654752440f));
}
__device__ __forceinline__ void gl_lds16(const u16* g, u16* l){
  __builtin_amdgcn_global_load_lds((const __attribute__((address_space(1))) void*)(g),
                                   (__attribute__((address_space(3))) void*)(l), 16, 0, 0);
}

// ---------------- K0: weights -> bf16 (g1 folded into w_qkv) ----------------
__global__ void prep_w_k(const float* __restrict__ wqkv, const float* __restrict__ g1,
                         const float* __restrict__ wout, u16* __restrict__ w1b,
                         u16* __restrict__ w2b){
  int i = blockIdx.x * 256 + threadIdx.x;
  if (i < 1536*512) {
    w1b[i] = f2bf(wqkv[i] * g1[i & 511]);
  } else {
    int j = i - 1536*512;
    w2b[j] = f2bf(wout[j]);
  }
}

// ------- K1: ChanLN over c, single global read via big-LDS staging ---------
__global__ __launch_bounds__(512) void ln1t_k(const float* __restrict__ fmap,
                                              u16* __restrict__ xlnT){
  int b = blockIdx.y, n0 = blockIdx.x * 32;
  int t = threadIdx.x;
  int lane = t & 63, wv = t >> 6;
  __shared__ float Lb[512][36];
  __shared__ u16 Tt[64][36];
  __shared__ float red1[8][8][4], red2[8][8][4];
  __shared__ float mean_s[32], rstd_s[32];

  int ng = t & 7;
  float s1[4] = {0,0,0,0}, s2[4] = {0,0,0,0};
  const float* fb = fmap + ((size_t)b*CD)*NS + n0 + ng*4;
  #pragma unroll
  for (int it = 0; it < 8; ++it){
    int q = it*512 + t;
    int c = q >> 3;
    f32x4 v = *(const f32x4*)&fb[(size_t)c*NS];
    *(f32x4*)&Lb[c][ng*4] = v;
    #pragma unroll
    for (int j = 0; j < 4; ++j){ s1[j] += v[j]; s2[j] += v[j]*v[j]; }
  }
  #pragma unroll
  for (int off = 8; off < 64; off <<= 1)
    #pragma unroll
    for (int j = 0; j < 4; ++j){
      s1[j] += __shfl_xor(s1[j], off, 64);
      s2[j] += __shfl_xor(s2[j], off, 64);
    }
  if (lane < 8){
    #pragma unroll
    for (int j = 0; j < 4; ++j){ red1[wv][lane][j] = s1[j]; red2[wv][lane][j] = s2[j]; }
  }
  __syncthreads();
  if (t < 32){
    int g = t >> 2, j = t & 3;
    float a = 0.f, bq = 0.f;
    #pragma unroll
    for (int w = 0; w < 8; ++w){ a += red1[w][g][j]; bq += red2[w][g][j]; }
    float mn = a * (1.f/512.f);
    float var = bq * (1.f/512.f) - mn*mn;
    mean_s[t] = mn; rstd_s[t] = rsqrtf(var + 1e-5f);
  }
  __syncthreads();

  for (int ct = 0; ct < 8; ++ct){
    {
      int cl = t >> 3, n4 = (t & 7) * 4;
      f32x4 v = *(const f32x4*)&Lb[ct*64 + cl][n4];
      u16x4 pk;
      #pragma unroll
      for (int j = 0; j < 4; ++j)
        pk[j] = f2bf((v[j] - mean_s[n4+j]) * rstd_s[n4+j]);
      *(u16x4*)&Tt[cl][n4] = pk;
    }
    __syncthreads();
    {
      int nr = t >> 4, c4 = t & 15;
      u16x4 w;
      #pragma unroll
      for (int j = 0; j < 4; ++j) w[j] = Tt[c4*4 + j][nr];
      *(u16x4*)&xlnT[((size_t)b*NS + n0 + nr)*CD + ct*64 + c4*4] = w;
    }
    __syncthreads();
  }
}

// ---------- K2: 256x256 GEMM, BK=32, 4-slot LDS ring, counted vmcnt --------
// C[b][o][n] = A[o][c] * B[b][n][c]^T. 512 thr / 8 waves (2M x 4N), per-wave
// 128x64. 16 K-tiles; stage runs 3 tiles ahead; tile-end wait vmcnt(8)
// (2 tiles in flight, never drained to 0 until epilogue). 2 phases/tile of
// {ds_read; stage 2; barrier; lgkm0; 16 MFMA; barrier}. Slot-XOR swizzle
// (2-bit) with pre-swizzled global source (rule #21).
__global__ __launch_bounds__(512, 2) void gemm1_k(const u16* __restrict__ A,
                                                  const u16* __restrict__ Bm,
                                                  u16* __restrict__ Cm){
  __shared__ u16 lds[4][16384];   // per slot: A[0..8192) 256x32, B[8192..16384)
  int bi = blockIdx.x;
  int xcd = bi & 7, r2 = bi >> 3;
  int gi = r2 / 6, yy = r2 - gi*6;
  int g  = gi*8 + xcd;
  int x  = g & 15, z = g >> 4;
  int o0 = yy*256, bn0 = x*256;
  int t = threadIdx.x;
  int lane = t & 63, wv = t >> 6;
  int wm = wv >> 2, wn = wv & 3;
  int fr = lane & 15, fg = lane >> 4;
  const u16* Ab = A + (size_t)o0*512;
  const u16* Bb = Bm + ((size_t)z*NS + bn0)*512;
  int rA = t >> 2, cx = t & 3;

  f32x4 acc[8][4];
  #pragma unroll
  for (int i=0;i<8;++i)
    #pragma unroll
    for (int j=0;j<4;++j) acc[i][j] = (f32x4){0.f,0.f,0.f,0.f};
  s16x8 afr[4], bfr[4];

  auto stA = [&](int slot, int kt, int bt){
    int r = bt*128 + rA;
    gl_lds16(Ab + (size_t)r*512 + kt + ((cx ^ (r&3))<<3), &lds[slot][bt*4096 + wv*512]);
  };
  auto stB = [&](int slot, int kt, int bt){
    int r = bt*128 + rA;
    gl_lds16(Bb + (size_t)r*512 + kt + ((cx ^ (r&3))<<3), &lds[slot][8192 + bt*4096 + wv*512]);
  };
  auto ldA = [&](int slot, int h){
    #pragma unroll
    for (int mi=0;mi<4;++mi){
      int R = wm*128 + (h*4+mi)*16 + fr;
      afr[mi] = *(const s16x8*)&lds[slot][R*32 + ((fg ^ (R&3))<<3)];
    }
  };
  auto ldB = [&](int slot){
    #pragma unroll
    for (int nj=0;nj<4;++nj){
      int R = wn*64 + nj*16 + fr;
      bfr[nj] = *(const s16x8*)&lds[slot][8192 + R*32 + ((fg ^ (R&3))<<3)];
    }
  };
  auto mm16 = [&](int h){
    #pragma unroll
    for (int mi=0;mi<4;++mi)
      #pragma unroll
      for (int nj=0;nj<4;++nj)
        acc[h*4+mi][nj] = __builtin_amdgcn_mfma_f32_16x16x32_bf16(
            afr[mi], bfr[nj], acc[h*4+mi][nj], 0,0,0);
  };

  // prologue: tiles 0,1,2 (4 loads each, consistent order); t0 landed
  #pragma unroll
  for (int p=0;p<3;++p){ stA(p,p*32,0); stB(p,p*32,0); stA(p,p*32,1); stB(p,p*32,1); }
  asm volatile("s_waitcnt vmcnt(8)" ::: "memory");
  SBAR; SCHED;

  #pragma unroll
  for (int kt=0; kt<16; ++kt){
    int slot = kt & 3, ns = (kt+3) & 3, kn = (kt+3)*32;
    // P1
    ldA(slot,0); ldB(slot);
    if (kt<13){ stA(ns,kn,0); stB(ns,kn,0); }
    SBAR; LGKM0; SCHED;
    PRIO1; mm16(0); PRIO0;
    SBAR; SCHED;
    // P2
    ldA(slot,1);
    if (kt<13){ stA(ns,kn,1); stB(ns,kn,1); }
    SBAR; LGKM0; SCHED;
    PRIO1; mm16(1); PRIO0;
    if (kt<13)       asm volatile("s_waitcnt vmcnt(8)" ::: "memory");
    else if (kt==13) asm volatile("s_waitcnt vmcnt(4)" ::: "memory");
    else if (kt==14) asm volatile("s_waitcnt vmcnt(0)" ::: "memory");
    SBAR; SCHED;
  }

  size_t cb = (size_t)z * 1536 * NS;
  #pragma unroll
  for (int mi=0;mi<8;++mi)
    #pragma unroll
    for (int nj=0;nj<4;++nj){
      int row = o0 + wm*128 + mi*16 + fg*4;
      int col = bn0 + wn*64 + nj*16 + fr;
      #pragma unroll
      for (int r=0;r<4;++r)
        Cm[cb + (size_t)(row+r)*NS + col] = f2bf(acc[mi][nj][r]);
    }
}

// ------ K6: full-column GEMM (512x128) + fused final ChanLN -> d_out -------
// out[b][o][n] = LN_c( w2[o][c] * gT[b][n][c]^T ) * g2. Block owns ALL 512
// channels for 128 n's: stats in-block, no y buffer, no ln2 pass.
// 8 waves (4M x 2N), BK=32, 3-slot ring, vmcnt(5).
__global__ __launch_bounds__(512, 2) void gemm2ln_k(const u16* __restrict__ A,
                                                    const u16* __restrict__ Bm,
                                                    const float* __restrict__ g2,
                                                    float* __restrict__ out){
  __shared__ u16 lds[3][20480];   // per slot: A[0..16384) 512x32, B[16384..20480) 128x32
  int x = blockIdx.x, z = blockIdx.y;
  int n0 = x*128;
  int t = threadIdx.x;
  int lane = t & 63, wv = t >> 6;
  int wm = wv >> 1, wn = wv & 1;
  int fr = lane & 15, fg = lane >> 4;
  const u16* Ab = A;
  const u16* Bb = Bm + ((size_t)z*NS + n0)*512;
  int rA = t >> 2, cx = t & 3;

  f32x4 acc[8][4];
  #pragma unroll
  for (int i=0;i<8;++i)
    #pragma unroll
    for (int j=0;j<4;++j) acc[i][j] = (f32x4){0.f,0.f,0.f,0.f};
  s16x8 afr[4], bfr[4];

  auto stA = [&](int slot, int kt, int bt){
    int r = bt*128 + rA;
    gl_lds16(Ab + (size_t)r*512 + kt + ((cx ^ (r&3))<<3), &lds[slot][bt*4096 + wv*512]);
  };
  auto stB = [&](int slot, int kt){
    int r = rA;
    gl_lds16(Bb + (size_t)r*512 + kt + ((cx ^ (r&3))<<3), &lds[slot][16384 + wv*512]);
  };
  auto ldA = [&](int slot, int h){
    #pragma unroll
    for (int mi=0;mi<4;++mi){
      int R = wm*128 + (h*4+mi)*16 + fr;
      afr[mi] = *(const s16x8*)&lds[slot][R*32 + ((fg ^ (R&3))<<3)];
    }
  };
  auto ldB = [&](int slot){
    #pragma unroll
    for (int nj=0;nj<4;++nj){
      int R = wn*64 + nj*16 + fr;
      bfr[nj] = *(const s16x8*)&lds[slot][16384 + R*32 + ((fg ^ (R&3))<<3)];
    }
  };
  auto mm16 = [&](int h){
    #pragma unroll
    for (int mi=0;mi<4;++mi)
      #pragma unroll
      for (int nj=0;nj<4;++nj)
        acc[h*4+mi][nj] = __builtin_amdgcn_mfma_f32_16x16x32_bf16(
            afr[mi], bfr[nj], acc[h*4+mi][nj], 0,0,0);
  };

  // prologue: tiles 0,1 (5 loads each: A0,A1,B,A2,A3)
  #pragma unroll
  for (int p=0;p<2;++p){ stA(p,p*32,0); stA(p,p*32,1); stB(p,p*32); stA(p,p*32,2); stA(p,p*32,3); }
  asm volatile("s_waitcnt vmcnt(5)" ::: "memory");
  SBAR; SCHED;

  #pragma unroll
  for (int kt=0; kt<16; ++kt){
    int slot = kt%3, ns = (kt+2)%3, kn = (kt+2)*32;
    // P1
    ldA(slot,0); ldB(slot);
    if (kt<14){ stA(ns,kn,0); stA(ns,kn,1); stB(ns,kn); }
    SBAR; LGKM0; SCHED;
    PRIO1; mm16(0); PRIO0;
    SBAR; SCHED;
    // P2
    ldA(slot,1);
    if (kt<14){ stA(ns,kn,2); stA(ns,kn,3); }
    SBAR; LGKM0; SCHED;
    PRIO1; mm16(1); PRIO0;
    if (kt<14)       asm volatile("s_waitcnt vmcnt(5)" ::: "memory");
    else if (kt==14) asm volatile("s_waitcnt vmcnt(0)" ::: "memory");
    SBAR; SCHED;
  }

  // ---- fused LN2: stats over all 512 rows per n-col, then write d_out ----
  __syncthreads();
  float* red1 = (float*)&lds[0][0];
  float* red2 = red1 + 512;
  float* ms   = red2 + 512;
  float* rs   = ms + 128;
  float s1[4], s2[4];
  #pragma unroll
  for (int nj=0;nj<4;++nj){
    float a = 0.f, b2 = 0.f;
    #pragma unroll
    for (int mi=0;mi<8;++mi)
      #pragma unroll
      for (int r=0;r<4;++r){ float v = acc[mi][nj][r]; a += v; b2 += v*v; }
    s1[nj] = a; s2[nj] = b2;
  }
  #pragma unroll
  for (int off=16; off<64; off<<=1)
    #pragma unroll
    for (int nj=0;nj<4;++nj){
      s1[nj] += __shfl_xor(s1[nj], off, 64);
      s2[nj] += __shfl_xor(s2[nj], off, 64);
    }
  if (fg == 0){
    #pragma unroll
    for (int nj=0;nj<4;++nj){
      int c = wn*64 + nj*16 + fr;
      red1[wm*128 + c] = s1[nj];
      red2[wm*128 + c] = s2[nj];
    }
  }
  __syncthreads();
  if (t < 128){
    float a  = red1[t] + red1[128+t] + red1[256+t] + red1[384+t];
    float b2 = red2[t] + red2[128+t] + red2[256+t] + red2[384+t];
    float mn = a * (1.f/512.f);
    float var = b2 * (1.f/512.f) - mn*mn;
    ms[t] = mn; rs[t] = rsqrtf(var + 1e-5f);
  }
  __syncthreads();
  float mc[4], rc[4];
  #pragma unroll
  for (int nj=0;nj<4;++nj){
    int c = wn*64 + nj*16 + fr;
    mc[nj] = ms[c]; rc[nj] = rs[c];
  }
  float* ob = out + (size_t)z*CD*NS + n0;
  #pragma unroll
  for (int mi=0;mi<8;++mi)
    #pragma unroll
    for (int r=0;r<4;++r){
      int row = wm*128 + mi*16 + fg*4 + r;
      float gg = g2[row];
      #pragma unroll
      for (int nj=0;nj<4;++nj)
        ob[(size_t)row*NS + wn*64 + nj*16 + fr] = (acc[mi][nj][r] - mc[nj])*rc[nj]*gg;
    }
}

// ------- K4: context partials (online k-softmax, local max per chunk) ------
__global__ __launch_bounds__(256) void ctxpart_k(const u16* __restrict__ qkv,
                                                 float* __restrict__ part,
                                                 float* __restrict__ mS){
  int chunk = blockIdx.x, bh = blockIdx.y;
  int b = bh >> 3, h = bh & 7;
  int t = threadIdx.x;
  int lane = t & 63, wv = t >> 6;
  int fr = lane & 15, fg = lane >> 4;
  __shared__ u16 KT[64*128];
  __shared__ u16 VT[64*128];
  __shared__ float invn_s[128];
  const u16* kb = qkv + ((size_t)(b*1536 + 512  + h*64))*NS;
  const u16* vb = qkv + ((size_t)(b*1536 + 1024 + h*64))*NS;
  int d = t >> 2, q = t & 3;

  float mloc = -3.0e38f;
  #pragma unroll
  for (int nt = 0; nt < 4; ++nt)
    #pragma unroll
    for (int s = 0; s < 4; ++s){
      u16x8 kk = *(const u16x8*)&kb[(size_t)d*NS + chunk*512 + nt*128 + q*32 + s*8];
      #pragma unroll
      for (int j = 0; j < 8; ++j) mloc = fmaxf(mloc, bf2f(kk[j]));
    }
  mloc = fmaxf(mloc, __shfl_xor(mloc, 1, 64));
  mloc = fmaxf(mloc, __shfl_xor(mloc, 2, 64));
  float sloc = 0.f;

  f32x4 acc[4][4];
  #pragma unroll
  for (int i=0;i<4;++i)
    #pragma unroll
    for (int j=0;j<4;++j) acc[i][j] = (f32x4){0.f,0.f,0.f,0.f};

  for (int nt = 0; nt < 4; ++nt){
    int n0 = chunk*512 + nt*128;
    if (nt) __syncthreads();
    u16x8 kreg[4];
    #pragma unroll
    for (int s = 0; s < 4; ++s){
      int c0 = q*32 + s*8;
      u16x8 vv = *(const u16x8*)&vb[(size_t)d*NS + n0 + c0];
      *(u16x8*)&VT[d*128 + (c0 ^ ((d&7)<<3))] = vv;
      kreg[s] = *(const u16x8*)&kb[(size_t)d*NS + n0 + c0];
    }
    __syncthreads();
    if (t < 128){
      float ss = 0.f;
      #pragma unroll
      for (int e = 0; e < 64; ++e){
        float xv = bf2f(VT[e*128 + (t ^ ((e&7)<<3))]);
        ss += xv*xv;
      }
      invn_s[t] = rsqrtf(ss);
    }
    __syncthreads();
    #pragma unroll
    for (int s = 0; s < 4; ++s){
      int c0 = q*32 + s*8;
      u16x8 kk = kreg[s];
      u16x8 ek;
      #pragma unroll
      for (int j = 0; j < 8; ++j){
        float e = __expf(bf2f(kk[j]) - mloc);
        sloc += e;
        ek[j] = f2bf(e * invn_s[c0 + j]);
      }
      *(u16x8*)&KT[d*128 + (c0 ^ ((d&7)<<3))] = ek;
    }
    __syncthreads();
    int kc = wv*32 + fg*8;
    s16x8 af[4], bfr[4];
    #pragma unroll
    for (int i=0;i<4;++i){
      int ra = i*16 + fr;
      af[i]  = *(const s16x8*)&KT[ra*128 + (kc ^ ((ra&7)<<3))];
      bfr[i] = *(const s16x8*)&VT[ra*128 + (kc ^ ((ra&7)<<3))];
    }
    #pragma unroll
    for (int i=0;i<4;++i)
      #pragma unroll
      for (int j=0;j<4;++j)
        acc[i][j] = __builtin_amdgcn_mfma_f32_16x16x32_bf16(af[i], bfr[j], acc[i][j], 0,0,0);
  }

  sloc += __shfl_xor(sloc, 1, 64);
  sloc += __shfl_xor(sloc, 2, 64);
  if (q == 0){
    size_t mb = ((size_t)bh*8 + chunk)*128;
    mS[mb + d]      = mloc;
    mS[mb + 64 + d] = sloc;
  }

  float* buf0 = (float*)KT;
  float* buf1 = (float*)VT;
  auto dump = [&](float* bf){
    #pragma unroll
    for (int i=0;i<4;++i)
      #pragma unroll
      for (int j=0;j<4;++j)
        #pragma unroll
        for (int r=0;r<4;++r) bf[((i*4+j)*4+r)*64 + lane] = acc[i][j][r];
  };
  auto addin = [&](float* bf){
    #pragma unroll
    for (int i=0;i<4;++i)
      #pragma unroll
      for (int j=0;j<4;++j)
        #pragma unroll
        for (int r=0;r<4;++r) acc[i][j][r] += bf[((i*4+j)*4+r)*64 + lane];
  };
  __syncthreads();
  if (wv==1) dump(buf0);
  if (wv==3) dump(buf1);
  __syncthreads();
  if (wv==0) addin(buf0);
  if (wv==2) addin(buf1);
  __syncthreads();
  if (wv==2) dump(buf0);
  __syncthreads();
  if (wv==0){
    addin(buf0);
    float* pp = part + ((size_t)bh*8 + chunk)*4096;
    #pragma unroll
    for (int i=0;i<4;++i)
      #pragma unroll
      for (int j=0;j<4;++j)
        #pragma unroll
        for (int r=0;r<4;++r)
          pp[(i*16+fg*4+r)*64 + j*16+fr] = acc[i][j][r];
  }
}

// ---- K4b: merge 8 chunk partials with online-softmax scales -> ctx --------
__global__ void ctxred_k(const float* __restrict__ part, const float* __restrict__ mS,
                         float* __restrict__ ctx){
  int bh = blockIdx.x, t = threadIdx.x;
  __shared__ float fs[8][64];
  if (t < 64){
    int d = t;
    float mc[8];
    float mx = -3.0e38f;
    #pragma unroll
    for (int c=0;c<8;++c){ mc[c] = mS[((size_t)bh*8 + c)*128 + d]; mx = fmaxf(mx, mc[c]); }
    float es[8]; float denom = 0.f;
    #pragma unroll
    for (int c=0;c<8;++c){
      es[c] = __expf(mc[c] - mx);
      denom += es[c] * mS[((size_t)bh*8 + c)*128 + 64 + d];
    }
    float inv = 1.0f / (denom * 4096.0f);
    #pragma unroll
    for (int c=0;c<8;++c) fs[c][d] = es[c] * inv;
  }
  __syncthreads();
  #pragma unroll
  for (int i=0;i<16;++i){
    int idx = t + i*256;
    int d = idx >> 6;
    float s = 0.f;
    #pragma unroll
    for (int ch=0; ch<8; ++ch) s += fs[ch][d] * part[((size_t)bh*8 + ch)*4096 + idx];
    ctx[(size_t)bh*4096 + idx] = s;
  }
}

// ------- K5: out = softmax_feat(q)*scale @ ctx  via MFMA, GELU, gT[b][n][c] -
__global__ __launch_bounds__(256) void attnout_k(const u16* __restrict__ qkv,
                                                 const float* __restrict__ ctx,
                                                 u16* __restrict__ gT){
  int bh = blockIdx.y;
  int b = bh >> 3, h = bh & 7;
  int n0 = blockIdx.x * 256;
  int t = threadIdx.x;
  int lane = t & 63, wv = t >> 6;
  int fr = lane & 15, fg = lane >> 4;
  __shared__ u16 P[256][72];
  __shared__ u16 cT[64][72];

  const float* cs = ctx + (size_t)bh*4096;
  #pragma unroll
  for (int i=0;i<16;++i){
    int idx = i*256 + t;
    int d = idx >> 6, e = idx & 63;
    cT[e][d] = f2bf(cs[idx]);
  }

  const u16* qb = qkv + ((size_t)(b*1536 + h*64))*NS + n0 + t;
  float p[64];
  #pragma unroll
  for (int d=0; d<64; ++d) p[d] = bf2f(qb[(size_t)d*NS]);
  float m = p[0];
  #pragma unroll
  for (int d=1; d<64; ++d) m = fmaxf(m, p[d]);
  float s = 0.f;
  #pragma unroll
  for (int d=0; d<64; ++d){ p[d] = __expf(p[d]-m); s += p[d]; }
  float inv = 0.125f / s;
  #pragma unroll
  for (int d0=0; d0<8; ++d0){
    u16x8 pk;
    #pragma unroll
    for (int j=0;j<8;++j) pk[j] = f2bf(p[d0*8+j] * inv);
    *(u16x8*)&P[t][d0*8] = pk;
  }
  __syncthreads();

  f32x4 acc[4][4];
  #pragma unroll
  for (int i=0;i<4;++i)
    #pragma unroll
    for (int j=0;j<4;++j) acc[i][j] = (f32x4){0.f,0.f,0.f,0.f};
  #pragma unroll
  for (int k=0; k<2; ++k){
    s16x8 af[4], bfr[4];
    #pragma unroll
    for (int i=0;i<4;++i){
      af[i]  = *(const s16x8*)&P[wv*64 + i*16 + fr][k*32 + fg*8];
      bfr[i] = *(const s16x8*)&cT[i*16 + fr][k*32 + fg*8];
    }
    #pragma unroll
    for (int i=0;i<4;++i)
      #pragma unroll
      for (int j=0;j<4;++j)
        acc[i][j] = __builtin_amdgcn_mfma_f32_16x16x32_bf16(af[i], bfr[j], acc[i][j], 0,0,0);
  }

  #pragma unroll
  for (int i=0;i<4;++i)
    #pragma unroll
    for (int j=0;j<4;++j)
      #pragma unroll
      for (int r=0;r<4;++r)
        P[wv*64 + i*16 + fg*4 + r][j*16 + fr] = f2bf(gelu_f(acc[i][j][r]));

  int sub = lane >> 4, e4 = (lane & 15) * 4;
  #pragma unroll
  for (int it=0; it<16; ++it){
    int row = wv*64 + it*4 + sub;
    *(u16x4*)&gT[((size_t)b*NS + n0 + row)*CD + h*64 + e4] = *(u16x4*)&P[row][e4];
  }
}

extern "C" void kernel_launch(void* const* d_in, const int* in_sizes, int n_in,
                              void* d_out, int out_size, void* d_ws, size_t ws_size,
                              hipStream_t stream) {
  const float* fmap = (const float*)d_in[0];
  const float* g1   = (const float*)d_in[1];
  const float* wqkv = (const float*)d_in[2];
  const float* wout = (const float*)d_in[3];
  const float* g2   = (const float*)d_in[4];
  float* out = (float*)d_out;

  char* ws = (char*)d_ws;
  size_t off = 0;
  auto alloc = [&](size_t bytes) -> void* {
    void* p = ws + off;
    off += (bytes + 255) & ~(size_t)255;
    return p;
  };
  u16*   qkv  = (u16*)alloc((size_t)16*1536*4096*2);
  u16*   xlnT = (u16*)alloc((size_t)16*4096*512*2);    // reused as gT
  u16*   gT   = xlnT;
  float* part = (float*)alloc((size_t)128*8*4096*4);
  float* mS   = (float*)alloc((size_t)128*8*128*4);
  float* ctx  = (float*)alloc((size_t)128*4096*4);
  u16*   w1b  = (u16*)alloc((size_t)1536*512*2);
  u16*   w2b  = (u16*)alloc((size_t)512*512*2);
  if (off > ws_size) return;

  prep_w_k<<<4096, 256, 0, stream>>>(wqkv, g1, wout, w1b, w2b);
  ln1t_k<<<dim3(128,16), 512, 0, stream>>>(fmap, xlnT);
  gemm1_k<<<1536, 512, 0, stream>>>(w1b, xlnT, qkv);
  ctxpart_k<<<dim3(8,128), 256, 0, stream>>>(qkv, part, mS);
  ctxred_k<<<128, 256, 0, stream>>>(part, mS, ctx);
  attnout_k<<<dim3(16,128), 256, 0, stream>>>(qkv, ctx, gT);
  gemm2ln_k<<<dim3(32,16), 512, 0, stream>>>(w2b, gT, g2, out);
}